// Round 2
// baseline (10810.810 us; speedup 1.0000x reference)
//
#include <hip/hip_runtime.h>

// ---------------------------------------------------------------------------
// 2-layer ReLU RNN, B=64 T=2048 IN=256 H=512 C=128. fp32 inputs (runtime
// dtype detect kept), output dtype matches input.
//
// Round-7: round-6 cross-layer pipelined fusion + flow-control FIX.
// One 32-WG kernel runs BOTH layer scans concurrently: WGs 0-15 = layer 0,
// WGs 16-31 = layer 1 (input projection folded into its recurrent MFMA
// chain, K=1024 over [h0_t ; h1_{t-1}]). h0_t crosses layers via hex0
// tagged-u64 device-scope atomic exchange.
//
// FIX vs round-6: publish of step t destroys step t-NBUF in the exchange
// ring; the throttle only certifies layer-1 consumed step t-LAG. Round-6
// had LAG=6 > NBUF=2 -> layer-0 overwrote unread words whenever layer-1
// lagged >2 (tag gone forever -> guard expiry -> silent wrong data,
// absmax 5e-2). Invariant: LAG <= NBUF. Now hex0 is 4-deep (t&3) and
// LAG=3 (one spare buffer margin). Tag safety: same-buffer stale distance
// 4 -> 2-bit tag (cycle 8) differs by 2; prev-run residue unreachable
// (consumer of t has observed t-1 => buffer already rewritten this run);
// 0xAA poison only aliases tag 3 (first at t=6, buffer rewritten by then).
// hex1 (intra-layer, sibling lead <= 2) stays 2-deep.
// All spins keep guard limits -> no hangs, worst case wrong data.
// ---------------------------------------------------------------------------

typedef unsigned short u16;
typedef unsigned int u32;
typedef unsigned long long u64;
typedef _Float16 f16;
typedef _Float16 half8 __attribute__((ext_vector_type(8)));
typedef float float4v __attribute__((ext_vector_type(4)));

#define T_LEN 2048
#define H_DIM 512
#define B_SZ 64
#define SGN 0x8000800080008000ull
#define VMASK 0x7fff7fff7fff7fffull
#define SPIN_LIM (1 << 15)
#define LAG 3

__device__ __forceinline__ float bf2f(u16 u) {
    union { u32 i; float f; } v; v.i = ((u32)u) << 16; return v.f;
}
__device__ __forceinline__ u16 f2bf(float f) {
    u32 x = __float_as_uint(f);
    u32 r = (x + 0x7fffu + ((x >> 16) & 1u)) >> 16;
    return (u16)r;
}
__device__ __forceinline__ float loadf(const void* p, size_t i, int dt) {
    return dt ? ((const float*)p)[i] : bf2f(((const u16*)p)[i]);
}
__device__ __forceinline__ half8 cvt8_bf16(uint4 v) {
    half8 h;
    h[0] = (f16)bf2f((u16)(v.x & 0xffff)); h[1] = (f16)bf2f((u16)(v.x >> 16));
    h[2] = (f16)bf2f((u16)(v.y & 0xffff)); h[3] = (f16)bf2f((u16)(v.y >> 16));
    h[4] = (f16)bf2f((u16)(v.z & 0xffff)); h[5] = (f16)bf2f((u16)(v.z >> 16));
    h[6] = (f16)bf2f((u16)(v.w & 0xffff)); h[7] = (f16)bf2f((u16)(v.w >> 16));
    return h;
}
// 2-bit tag for step t, encoded in the 4 f16 sign bits of a u64.
__device__ __forceinline__ u64 tagmask(int t) {
    int tg = (t >> 1) & 3;
    return ((tg & 1) ? 0x0000800000008000ull : 0ull) |
           ((tg & 2) ? 0x8000000080000000ull : 0ull);
}

// --------------------------- dtype detection -------------------------------
__global__ void detect_kernel(const u16* __restrict__ xr, int* __restrict__ dtf,
                              u32* __restrict__ prog) {
    int lane = threadIdx.x;
    u16 u0 = xr[(lane * 2 + 0) * 2];
    u16 u1 = xr[(lane * 2 + 1) * 2];
    int e0 = (u0 >> 7) & 0xff, e1 = (u1 >> 7) & 0xff;
    int c0 = (e0 >= 0x60 && e0 <= 0x8f) ? 1 : 0;
    int c1 = (e1 >= 0x60 && e1 <= 0x8f) ? 1 : 0;
    int tot = __popcll(__ballot(c0)) + __popcll(__ballot(c1));
    if (lane == 0) *dtf = (tot >= 96) ? 0 : 1;   // 0 = bf16, 1 = fp32
    if (lane < 16) prog[lane] = 0;               // layer-1 progress reset
}

// --------------------------- prep kernels ----------------------------------
__global__ void cvt_w_kernel(const void* __restrict__ in, f16* __restrict__ out,
                             int n, const int* __restrict__ dtf) {
    int dt = *dtf;
    for (int i = blockIdx.x * blockDim.x + threadIdx.x; i < n; i += gridDim.x * blockDim.x)
        out[i] = (f16)loadf(in, i, dt);
}

__global__ void bias_kernel(const void* __restrict__ bi, const void* __restrict__ bh,
                            float* __restrict__ bias, const int* __restrict__ dtf) {
    int dt = *dtf;
    int i = blockIdx.x * blockDim.x + threadIdx.x;
    if (i < H_DIM) bias[i] = loadf(bi, i, dt) + loadf(bh, i, dt);
}

__global__ void fcb_kernel(const void* __restrict__ in, float* __restrict__ out,
                           const int* __restrict__ dtf) {
    int i = threadIdx.x;
    if (i < 128) out[i] = loadf(in, i, *dtf);
}

// --------------------------- tiled MFMA GEMM -------------------------------
// C[m,n] = sum_k A[m,k]*Bw[n,k] + bias[n], fp16 MFMA, fp16 out, N=512.
// RAW=1: A is raw x ([B,T,K], dtf dtype), chunk-local row m -> b*T + t0+tt.
template<int RAW>
__global__ __launch_bounds__(256)
void gemm_tiled(const void* __restrict__ Araw, const f16* __restrict__ Bw,
                const float* __restrict__ bias, f16* __restrict__ C,
                int lgTc, int t_off, int K, const int* __restrict__ dtf)
{
    __shared__ f16 As[64][40];
    __shared__ f16 Bs[64][40];
    const int dt = RAW ? *dtf : 0;
    const int m0 = blockIdx.x * 64, n0 = blockIdx.y * 64;
    const int tid = threadIdx.x;
    const int wv = tid >> 6, lane = tid & 63;
    const int lr = lane & 15, quad = lane >> 4;
    const int srow = tid >> 2, skq = tid & 3;

    float4v acc[4] = {{0.f,0.f,0.f,0.f},{0.f,0.f,0.f,0.f},{0.f,0.f,0.f,0.f},{0.f,0.f,0.f,0.f}};

    size_t arow;
    {
        int ml = m0 + srow;
        if (RAW) {
            int b = ml >> lgTc, tt = ml & ((1 << lgTc) - 1);
            arow = (size_t)b * T_LEN + t_off + tt;
        } else arow = (size_t)ml;
    }
    const f16* pb = Bw + (size_t)(n0 + srow) * K + skq * 8;

    for (int k0 = 0; k0 < K; k0 += 32) {
        half8 av;
        if (RAW) {
            if (dt) {
                const float* ap = (const float*)Araw + arow * K + k0 + skq * 8;
                float4v f0 = *(const float4v*)ap;
                float4v f1 = *(const float4v*)(ap + 4);
                av[0]=(f16)f0[0]; av[1]=(f16)f0[1]; av[2]=(f16)f0[2]; av[3]=(f16)f0[3];
                av[4]=(f16)f1[0]; av[5]=(f16)f1[1]; av[6]=(f16)f1[2]; av[7]=(f16)f1[3];
            } else {
                av = cvt8_bf16(*(const uint4*)((const u16*)Araw + arow * K + k0 + skq * 8));
            }
        } else {
            av = *(const half8*)((const f16*)Araw + arow * K + k0 + skq * 8);
        }
        half8 bv = *(const half8*)(pb + k0);
        __syncthreads();
        *(half8*)&As[srow][skq * 8] = av;
        *(half8*)&Bs[srow][skq * 8] = bv;
        __syncthreads();
        half8 bf = *(const half8*)&Bs[wv * 16 + lr][quad * 8];
#pragma unroll
        for (int mt = 0; mt < 4; ++mt) {
            half8 af = *(const half8*)&As[mt * 16 + lr][quad * 8];
            acc[mt] = __builtin_amdgcn_mfma_f32_16x16x32_f16(af, bf, acc[mt], 0, 0, 0);
        }
    }
    const int n = n0 + wv * 16 + lr;
    const float bval = bias[n];
#pragma unroll
    for (int mt = 0; mt < 4; ++mt) {
#pragma unroll
        for (int i = 0; i < 4; ++i) {
            int m = m0 + mt * 16 + quad * 4 + i;
            C[(size_t)m * H_DIM + n] = (f16)(acc[mt][i] + bval);
        }
    }
}

// --------------------------- fused 2-layer scan ----------------------------
// grid = 32. bid<16: layer 0 (wid=bid); bid>=16: layer 1 (wid=bid-16).
// WG (r = wid>>2, cg = wid&3) -> batch rows [r*16,+16), cols [cg*128,+128).
// 256 thr = 4 waves; wave w: cols [cg*128+w*32,+32).
// hex0: [4][64][128] u64 ring (buffer t&3, 2-bit sign tag) -- layer-0
// publish, layer-0 siblings + layer-1 consume. hex1: [2][64][128] (t&1),
// intra-layer-1 only. prog[16]: layer-1 WG wid stores t+1 after consuming
// h0_t; layer-0 blocks publish of t until prog >= t-LAG+1 (LAG=3 <= NBUF=4).
__global__ __launch_bounds__(256, 1)
void rnn_fused_scan(const f16* __restrict__ pre0,    // [B,Tc,H] chunk-local
                    const f16* __restrict__ Whh0,    // [H,H] fp16
                    const f16* __restrict__ Wih1,    // [H,H] fp16
                    const f16* __restrict__ Whh1,    // [H,H] fp16
                    const float* __restrict__ bias1, // [H] fp32
                    u64* __restrict__ hex0,          // [4][64][128]
                    u64* __restrict__ hex1,          // [2][64][128]
                    f16* __restrict__ hc0,           // [B,H] layer-0 carry
                    f16* __restrict__ hc1,           // [B,H] layer-1 carry
                    u32* __restrict__ prog,          // [16]
                    int t0, int Tc,
                    float* __restrict__ h_last)      // [B,H] fp32
{
    __shared__ f16 stage[2][16 * 512];   // h double buffer (granule-XOR swizzle)
    __shared__ f16 sH0[16 * 512];        // layer-1 only: h0_t staging
    const int bid = blockIdx.x;
    const int layer = bid >> 4;
    const int wid = bid & 15;
    const int r = wid >> 2, cg = wid & 3;
    const int rows0 = r * 16;
    const int tid = threadIdx.x;
    const int w = tid >> 6, lane = tid & 63;
    const int lr = lane & 15, quad = lane >> 4;
    const int c0w = cg * 128 + w * 32;
    // Remote-read assignment: thread covers u64-cols [rc8, rc8+8) of row rrow.
    const int rrow = tid >> 4;
    const int rc8 = (tid & 15) * 8;
    const bool mine = ((tid & 15) >> 2) == cg;   // own-slice words -> skip spin

    if (layer == 0) {
        // ================= layer 0 (round-5 scan + throttle) =================
        half8 Bf[2][16];
#pragma unroll
        for (int j = 0; j < 2; ++j)
#pragma unroll
            for (int kc = 0; kc < 16; ++kc)
                Bf[j][kc] = *(const half8*)(Whh0 + (size_t)(c0w + j * 16 + lr) * H_DIM
                                            + kc * 32 + quad * 8);

        if (t0 > 0) {
            int row = tid >> 4, g0 = (tid & 15) * 4;
#pragma unroll
            for (int gq = 0; gq < 4; ++gq) {
                int g = g0 + gq;
                *(uint4*)&stage[(t0 - 1) & 1][row * 512 + ((g ^ (row & 7)) * 8)] =
                    *(const uint4*)(hc0 + (size_t)(rows0 + row) * H_DIM + g * 8);
            }
        }
        __syncthreads();

        for (int tt = 0; tt < Tc; ++tt) {
            const int t = t0 + tt;
            const int p = (t - 1) & 1, np = t & 1;
            const int nb = t & 3;              // hex0 ring slot
            const u64 em = tagmask(t);
            const int need = t - LAG;          // layer-1 must have consumed h0_need
            const u32 want = (u32)(need + 1);

            // Early-issue throttle RMW (latency hides under pv load + MFMA).
            u32 pvv = 0xffffffffu;
            if (need >= 0 && lane < 4)
                pvv = __hip_atomic_fetch_or(&prog[r * 4 + lane], 0u,
                                            __ATOMIC_RELAXED, __HIP_MEMORY_SCOPE_AGENT);

            // Prefetch pre_t (independent of the h chain).
            float pv[2][4];
#pragma unroll
            for (int j = 0; j < 2; ++j)
#pragma unroll
                for (int i = 0; i < 4; ++i)
                    pv[j][i] = (float)pre0[((size_t)(rows0 + quad * 4 + i) * Tc + tt) * H_DIM
                                           + c0w + j * 16 + lr];

            float4v acc0 = {0.f,0.f,0.f,0.f}, acc1 = {0.f,0.f,0.f,0.f};
            if (t > 0) {
                const f16* sb = stage[p];
#pragma unroll
                for (int kc = 0; kc < 16; ++kc) {
                    half8 a = *(const half8*)&sb[lr * 512 + (((kc * 4 + quad) ^ (lr & 7)) * 8)];
                    acc0 = __builtin_amdgcn_mfma_f32_16x16x32_f16(a, Bf[0][kc], acc0, 0, 0, 0);
                    acc1 = __builtin_amdgcn_mfma_f32_16x16x32_f16(a, Bf[1][kc], acc1, 0, 0, 0);
                }
            }

            // Compute h_t slice; write own values (untagged) into stage[np].
            f16* sw = stage[np];
            f16 hv16[2][4];
#pragma unroll
            for (int j = 0; j < 2; ++j) {
                const float4v& a = j ? acc1 : acc0;
#pragma unroll
                for (int i = 0; i < 4; ++i) {
                    float hval = fmaxf(a[i] + pv[j][i], 0.f);
                    hv16[j][i] = (f16)hval;
                    int row = quad * 4 + i, lc = c0w + j * 16 + lr;
                    sw[row * 512 + ((lc >> 3) ^ (row & 7)) * 8 + (lc & 7)] = hv16[j][i];
                }
            }
            if (tt == Tc - 1) {
#pragma unroll
                for (int j = 0; j < 2; ++j)
#pragma unroll
                    for (int i = 0; i < 4; ++i)
                        hc0[(size_t)(rows0 + quad * 4 + i) * H_DIM + c0w + j * 16 + lr] =
                            hv16[j][i];
            }
            __syncthreads();   // own-slice stage writes visible to publishers

            // Throttle resolve (per-wave). Publishing t destroys ring slot of
            // step t-4; LAG=3 certifies layer-1 consumed t-3 -> slot is dead.
            if (need >= 0) {
                bool ok = __all((lane < 4) ? (pvv >= want) : 1);
                int g = 0;
                while (!ok && g < SPIN_LIM) {
                    if (lane < 4)
                        pvv = __hip_atomic_fetch_or(&prog[r * 4 + lane], 0u,
                                                    __ATOMIC_RELAXED,
                                                    __HIP_MEMORY_SCOPE_AGENT);
                    ok = __all((lane < 4) ? (pvv >= want) : 1);
                    ++g;
                }
            }

            // Publish own 2 u64 (tagged) via device-scope atomic exchange.
            {
                int row = tid >> 4, poc = (tid & 15) * 2, cu = cg * 32 + poc;
                uint4 q4 = *(const uint4*)&stage[np][row * 512 + (((cu >> 1) ^ (row & 7)) * 8)];
                u64 v0 = (((u64)q4.y) << 32) | q4.x;
                u64 v1 = (((u64)q4.w) << 32) | q4.z;
                u64* dst = hex0 + ((size_t)nb * 64 + rows0 + row) * 128;
                (void)__hip_atomic_exchange(&dst[cu], v0 | em, __ATOMIC_RELAXED,
                                            __HIP_MEMORY_SCOPE_AGENT);
                (void)__hip_atomic_exchange(&dst[cu + 1], v1 | em, __ATOMIC_RELAXED,
                                            __HIP_MEMORY_SCOPE_AGENT);
            }

            // Spin-read the 3 sibling slices (tag-validated), store into stage[np].
            if (!mine) {
                u64* src = hex0 + ((size_t)nb * 64 + rows0 + rrow) * 128;
                u64 vv[8];
                int pend = 0xff, guard = 0;
                while (pend && guard < SPIN_LIM) {
#pragma unroll
                    for (int q = 0; q < 8; ++q)
                        if (pend & (1 << q))
                            vv[q] = __hip_atomic_fetch_or(&src[rc8 + q], 0ull,
                                                          __ATOMIC_RELAXED,
                                                          __HIP_MEMORY_SCOPE_AGENT);
#pragma unroll
                    for (int q = 0; q < 8; ++q)
                        if ((pend & (1 << q)) && ((vv[q] & SGN) == em))
                            pend &= ~(1 << q);
                    ++guard;
                }
#pragma unroll
                for (int q = 0; q < 8; ++q) {
                    int cu = rc8 + q;
                    *(u64*)&stage[np][rrow * 512 + ((cu >> 1) ^ (rrow & 7)) * 8 + (cu & 1) * 4] =
                        vv[q] & VMASK;
                }
            }
            __syncthreads();   // stage[np] complete for step t+1
        }
    } else {
        // ================= layer 1 (fused input-proj + recurrence) ===========
        half8 BfI[2][16], BfH[2][16];
#pragma unroll
        for (int j = 0; j < 2; ++j)
#pragma unroll
            for (int kc = 0; kc < 16; ++kc) {
                BfI[j][kc] = *(const half8*)(Wih1 + (size_t)(c0w + j * 16 + lr) * H_DIM
                                             + kc * 32 + quad * 8);
                BfH[j][kc] = *(const half8*)(Whh1 + (size_t)(c0w + j * 16 + lr) * H_DIM
                                             + kc * 32 + quad * 8);
            }
        float bvv[2] = { bias1[c0w + lr], bias1[c0w + 16 + lr] };

        if (t0 > 0) {
            int row = tid >> 4, g0 = (tid & 15) * 4;
#pragma unroll
            for (int gq = 0; gq < 4; ++gq) {
                int g = g0 + gq;
                *(uint4*)&stage[(t0 - 1) & 1][row * 512 + ((g ^ (row & 7)) * 8)] =
                    *(const uint4*)(hc1 + (size_t)(rows0 + row) * H_DIM + g * 8);
            }
        }
        __syncthreads();

        for (int tt = 0; tt < Tc; ++tt) {
            const int t = t0 + tt;
            const int p = (t - 1) & 1, np = t & 1;
            const int nb = t & 3;              // hex0 ring slot
            const u64 em = tagmask(t);

            // 1. Spin-read ALL 128 u64-cols of our 16 rows of h0_t -> sH0.
            {
                u64* src = hex0 + ((size_t)nb * 64 + rows0 + rrow) * 128;
                u64 vv[8];
                int pend = 0xff, guard = 0;
                while (pend && guard < SPIN_LIM) {
#pragma unroll
                    for (int q = 0; q < 8; ++q)
                        if (pend & (1 << q))
                            vv[q] = __hip_atomic_fetch_or(&src[rc8 + q], 0ull,
                                                          __ATOMIC_RELAXED,
                                                          __HIP_MEMORY_SCOPE_AGENT);
#pragma unroll
                    for (int q = 0; q < 8; ++q)
                        if ((pend & (1 << q)) && ((vv[q] & SGN) == em))
                            pend &= ~(1 << q);
                    ++guard;
                }
#pragma unroll
                for (int q = 0; q < 8; ++q) {
                    int cu = rc8 + q;
                    *(u64*)&sH0[rrow * 512 + ((cu >> 1) ^ (rrow & 7)) * 8 + (cu & 1) * 4] =
                        vv[q] & VMASK;
                }
            }
            __syncthreads();   // sH0 complete; all hex0[t] reads done

            // 2. Report consumption of h0_t (unblocks layer-0's step t+LAG).
            if (tid == 0)
                (void)__hip_atomic_exchange(&prog[wid], (u32)(t + 1),
                                            __ATOMIC_RELAXED, __HIP_MEMORY_SCOPE_AGENT);

            // 3. Fused K=1024 MFMA chain: h0_t @ Wih1^T + h1_{t-1} @ Whh1^T.
            float4v acc0 = {0.f,0.f,0.f,0.f}, acc1 = {0.f,0.f,0.f,0.f};
#pragma unroll
            for (int kc = 0; kc < 16; ++kc) {
                half8 a = *(const half8*)&sH0[lr * 512 + (((kc * 4 + quad) ^ (lr & 7)) * 8)];
                acc0 = __builtin_amdgcn_mfma_f32_16x16x32_f16(a, BfI[0][kc], acc0, 0, 0, 0);
                acc1 = __builtin_amdgcn_mfma_f32_16x16x32_f16(a, BfI[1][kc], acc1, 0, 0, 0);
            }
            if (t > 0) {
                const f16* sb = stage[p];
#pragma unroll
                for (int kc = 0; kc < 16; ++kc) {
                    half8 a = *(const half8*)&sb[lr * 512 + (((kc * 4 + quad) ^ (lr & 7)) * 8)];
                    acc0 = __builtin_amdgcn_mfma_f32_16x16x32_f16(a, BfH[0][kc], acc0, 0, 0, 0);
                    acc1 = __builtin_amdgcn_mfma_f32_16x16x32_f16(a, BfH[1][kc], acc1, 0, 0, 0);
                }
            }

            // 4. h1_t = relu(acc + bias1); write own slice into stage[np].
            f16* sw = stage[np];
            f16 hv16[2][4];
#pragma unroll
            for (int j = 0; j < 2; ++j) {
                const float4v& a = j ? acc1 : acc0;
#pragma unroll
                for (int i = 0; i < 4; ++i) {
                    float hval = fmaxf(a[i] + bvv[j], 0.f);
                    hv16[j][i] = (f16)hval;
                    int row = quad * 4 + i, lc = c0w + j * 16 + lr;
                    sw[row * 512 + ((lc >> 3) ^ (row & 7)) * 8 + (lc & 7)] = hv16[j][i];
                }
            }
            if (h_last && t == T_LEN - 1) {
#pragma unroll
                for (int j = 0; j < 2; ++j)
#pragma unroll
                    for (int i = 0; i < 4; ++i)
                        h_last[(size_t)(rows0 + quad * 4 + i) * H_DIM + c0w + j * 16 + lr] =
                            (float)hv16[j][i];
            }
            if (tt == Tc - 1) {
#pragma unroll
                for (int j = 0; j < 2; ++j)
#pragma unroll
                    for (int i = 0; i < 4; ++i)
                        hc1[(size_t)(rows0 + quad * 4 + i) * H_DIM + c0w + j * 16 + lr] =
                            hv16[j][i];
            }
            __syncthreads();   // own-slice stage writes visible to publishers

            // 5. Publish own 2 u64 (tagged) to hex1.
            {
                int row = tid >> 4, poc = (tid & 15) * 2, cu = cg * 32 + poc;
                uint4 q4 = *(const uint4*)&stage[np][row * 512 + (((cu >> 1) ^ (row & 7)) * 8)];
                u64 v0 = (((u64)q4.y) << 32) | q4.x;
                u64 v1 = (((u64)q4.w) << 32) | q4.z;
                u64* dst = hex1 + ((size_t)np * 64 + rows0 + row) * 128;
                (void)__hip_atomic_exchange(&dst[cu], v0 | em, __ATOMIC_RELAXED,
                                            __HIP_MEMORY_SCOPE_AGENT);
                (void)__hip_atomic_exchange(&dst[cu + 1], v1 | em, __ATOMIC_RELAXED,
                                            __HIP_MEMORY_SCOPE_AGENT);
            }

            // 6. Spin-read sibling h1 slices -> stage[np].
            if (!mine) {
                u64* src = hex1 + ((size_t)np * 64 + rows0 + rrow) * 128;
                u64 vv[8];
                int pend = 0xff, guard = 0;
                while (pend && guard < SPIN_LIM) {
#pragma unroll
                    for (int q = 0; q < 8; ++q)
                        if (pend & (1 << q))
                            vv[q] = __hip_atomic_fetch_or(&src[rc8 + q], 0ull,
                                                          __ATOMIC_RELAXED,
                                                          __HIP_MEMORY_SCOPE_AGENT);
#pragma unroll
                    for (int q = 0; q < 8; ++q)
                        if ((pend & (1 << q)) && ((vv[q] & SGN) == em))
                            pend &= ~(1 << q);
                    ++guard;
                }
#pragma unroll
                for (int q = 0; q < 8; ++q) {
                    int cu = rc8 + q;
                    *(u64*)&stage[np][rrow * 512 + ((cu >> 1) ^ (rrow & 7)) * 8 + (cu & 1) * 4] =
                        vv[q] & VMASK;
                }
            }
            __syncthreads();   // stage[np] complete for step t+1
        }
    }
}

// --------------------------- final FC --------------------------------------
__global__ void fc_kernel(const float* __restrict__ hlast, const f16* __restrict__ fcw,
                          const float* __restrict__ fcb, void* __restrict__ out,
                          const int* __restrict__ dtf) {
    int b = blockIdx.x, c = threadIdx.x;
    const float* hrow = hlast + b * H_DIM;
    const f16* wrow = fcw + (size_t)c * H_DIM;
    float s = fcb[c];
    for (int h0 = 0; h0 < H_DIM; h0 += 8) {
        half8 w = *(const half8*)(wrow + h0);
#pragma unroll
        for (int j = 0; j < 8; ++j) s += hrow[h0 + j] * (float)w[j];
    }
    if (*dtf) ((float*)out)[b * 128 + c] = s;
    else      ((u16*)out)[b * 128 + c] = f2bf(s);
}

// --------------------------- launch ----------------------------------------
extern "C" void kernel_launch(void* const* d_in, const int* in_sizes, int n_in,
                              void* d_out, int out_size, void* d_ws, size_t ws_size,
                              hipStream_t stream)
{
    const void* x     = d_in[0];
    const void* W_ih0 = d_in[1];
    const void* W_hh0 = d_in[2];
    const void* b_ih0 = d_in[3];
    const void* b_hh0 = d_in[4];
    const void* W_ih1 = d_in[5];
    const void* W_hh1 = d_in[6];
    const void* b_ih1 = d_in[7];
    const void* b_hh1 = d_in[8];
    const void* fc_w  = d_in[9];
    const void* fc_b  = d_in[10];

    char* ws = (char*)d_ws;
    int*   dtf   = (int*)(ws + 0);            //     64 B
    float* bias0 = (float*)(ws + 4096);       //   2048 B
    float* bias1 = (float*)(ws + 6144);       //   2048 B
    float* fcbf  = (float*)(ws + 8192);       //    512 B
    u32*   prog  = (u32*)(ws + 12288);        //     64 B
    float* hlast = (float*)(ws + 16384);      // 131072 B
    f16*   hc0   = (f16*)(ws + 147456);       //  65536 B
    f16*   hc1   = (f16*)(ws + 212992);       //  65536 B
    u64*   hex0  = (u64*)(ws + 278528);       // 262144 B [4][64][128] u64 ring
    u64*   hex1  = (u64*)(ws + 540672);       // 131072 B [2][64][128]
    f16*   Wih0f = (f16*)(ws + 671744);       // 262144 B
    f16*   Whh0f = (f16*)(ws + 933888);       // 524288 B
    f16*   Wih1f = (f16*)(ws + 1458176);      // 524288 B
    f16*   Whh1f = (f16*)(ws + 1982464);      // 524288 B
    f16*   fcwf  = (f16*)(ws + 2506752);      // 131072 B

    const size_t misc = 4u << 20;
    int Tc = 128;
    {
        auto need = [&](int tc) {
            return misc + (size_t)B_SZ * (size_t)tc * H_DIM * 2;   // single buffer
        };
        if (ws_size >= need(2048)) Tc = 2048;
        else if (ws_size >= need(1024)) Tc = 1024;
        else if (ws_size >= need(512)) Tc = 512;
        else if (ws_size >= need(256)) Tc = 256;
        else Tc = 128;
    }
    int lgTc = 31 - __builtin_clz((unsigned)Tc);
    f16* bufA = (f16*)(ws + misc);

    detect_kernel<<<dim3(1), dim3(64), 0, stream>>>((const u16*)x, dtf, prog);
    cvt_w_kernel<<<dim3(512), dim3(256), 0, stream>>>(W_ih0, Wih0f, H_DIM * 256, dtf);
    cvt_w_kernel<<<dim3(1024), dim3(256), 0, stream>>>(W_hh0, Whh0f, H_DIM * H_DIM, dtf);
    cvt_w_kernel<<<dim3(1024), dim3(256), 0, stream>>>(W_ih1, Wih1f, H_DIM * H_DIM, dtf);
    cvt_w_kernel<<<dim3(1024), dim3(256), 0, stream>>>(W_hh1, Whh1f, H_DIM * H_DIM, dtf);
    cvt_w_kernel<<<dim3(256), dim3(256), 0, stream>>>(fc_w, fcwf, 128 * H_DIM, dtf);
    bias_kernel<<<dim3(2), dim3(256), 0, stream>>>(b_ih0, b_hh0, bias0, dtf);
    bias_kernel<<<dim3(2), dim3(256), 0, stream>>>(b_ih1, b_hh1, bias1, dtf);
    fcb_kernel<<<dim3(1), dim3(128), 0, stream>>>(fc_b, fcbf, dtf);

    const int NC = T_LEN / Tc;
    const int mblocks = B_SZ * Tc / 64;
    for (int c = 0; c < NC; ++c) {
        const int t0 = c * Tc;
        gemm_tiled<1><<<dim3(mblocks, 8), 256, 0, stream>>>(
            x, Wih0f, bias0, bufA, lgTc, t0, 256, dtf);
        rnn_fused_scan<<<dim3(32), 256, 0, stream>>>(
            bufA, Whh0f, Wih1f, Whh1f, bias1, hex0, hex1, hc0, hc1, prog,
            t0, Tc, hlast);
    }
    fc_kernel<<<dim3(B_SZ), dim3(128), 0, stream>>>(hlast, fcwf, fcbf, d_out, dtf);
}

// Round 3
// 10236.187 us; speedup vs baseline: 1.0561x; 1.0561x over previous
//
#include <hip/hip_runtime.h>

// ---------------------------------------------------------------------------
// 2-layer ReLU RNN, B=64 T=2048 IN=256 H=512 C=128. fp32 inputs (runtime
// dtype detect kept), output dtype matches input.
//
// Round-8: round-7 pipelined fusion + exchange-latency fixes.
//  (1) All spin polls are relaxed AGENT-scope atomic LOADS (not fetch_or
//      RMWs): 8 u64 polls per 64B line pipeline into one round-trip instead
//      of 8 serialized line-locked RMWs, and no write-back traffic
//      (round-7: WRITE_SIZE 525MB for ~262MB of payload). Publishes are
//      relaxed AGENT-scope atomic STORES (write through to the coherence
//      point). Tag validation still rejects stale data and retries.
//  (2) Layer-1 prefetches h0_{t+1} (8 u64 loads issued right after step t's
//      MFMA chain) and validates at the top of step t+1 -- layer-0 runs
//      LAG=3 ahead so the data is normally resident; the hex0 round-trip
//      leaves layer-1's critical path. Tag-safe: slot (t+1)&3 can only hold
//      h0_{t-3} (already observed; tag differs by 2 mod 4) or h0_{t+1}.
// Flow control unchanged from round-7: hex0 4-deep ring (t&3), LAG=3<=4;
// hex1 2-deep (intra-layer sibling lead <=2). All spins guard-limited.
// ---------------------------------------------------------------------------

typedef unsigned short u16;
typedef unsigned int u32;
typedef unsigned long long u64;
typedef _Float16 f16;
typedef _Float16 half8 __attribute__((ext_vector_type(8)));
typedef float float4v __attribute__((ext_vector_type(4)));

#define T_LEN 2048
#define H_DIM 512
#define B_SZ 64
#define SGN 0x8000800080008000ull
#define VMASK 0x7fff7fff7fff7fffull
#define SPIN_LIM (1 << 15)
#define LAG 3

__device__ __forceinline__ float bf2f(u16 u) {
    union { u32 i; float f; } v; v.i = ((u32)u) << 16; return v.f;
}
__device__ __forceinline__ u16 f2bf(float f) {
    u32 x = __float_as_uint(f);
    u32 r = (x + 0x7fffu + ((x >> 16) & 1u)) >> 16;
    return (u16)r;
}
__device__ __forceinline__ float loadf(const void* p, size_t i, int dt) {
    return dt ? ((const float*)p)[i] : bf2f(((const u16*)p)[i]);
}
__device__ __forceinline__ half8 cvt8_bf16(uint4 v) {
    half8 h;
    h[0] = (f16)bf2f((u16)(v.x & 0xffff)); h[1] = (f16)bf2f((u16)(v.x >> 16));
    h[2] = (f16)bf2f((u16)(v.y & 0xffff)); h[3] = (f16)bf2f((u16)(v.y >> 16));
    h[4] = (f16)bf2f((u16)(v.z & 0xffff)); h[5] = (f16)bf2f((u16)(v.z >> 16));
    h[6] = (f16)bf2f((u16)(v.w & 0xffff)); h[7] = (f16)bf2f((u16)(v.w >> 16));
    return h;
}
// 2-bit tag for step t, encoded in the 4 f16 sign bits of a u64.
__device__ __forceinline__ u64 tagmask(int t) {
    int tg = (t >> 1) & 3;
    return ((tg & 1) ? 0x0000800000008000ull : 0ull) |
           ((tg & 2) ? 0x8000000080000000ull : 0ull);
}
__device__ __forceinline__ u64 aload(u64* p) {
    return __hip_atomic_load(p, __ATOMIC_RELAXED, __HIP_MEMORY_SCOPE_AGENT);
}
__device__ __forceinline__ void astore(u64* p, u64 v) {
    __hip_atomic_store(p, v, __ATOMIC_RELAXED, __HIP_MEMORY_SCOPE_AGENT);
}

// --------------------------- dtype detection -------------------------------
__global__ void detect_kernel(const u16* __restrict__ xr, int* __restrict__ dtf,
                              u32* __restrict__ prog) {
    int lane = threadIdx.x;
    u16 u0 = xr[(lane * 2 + 0) * 2];
    u16 u1 = xr[(lane * 2 + 1) * 2];
    int e0 = (u0 >> 7) & 0xff, e1 = (u1 >> 7) & 0xff;
    int c0 = (e0 >= 0x60 && e0 <= 0x8f) ? 1 : 0;
    int c1 = (e1 >= 0x60 && e1 <= 0x8f) ? 1 : 0;
    int tot = __popcll(__ballot(c0)) + __popcll(__ballot(c1));
    if (lane == 0) *dtf = (tot >= 96) ? 0 : 1;   // 0 = bf16, 1 = fp32
    if (lane < 16) prog[lane] = 0;               // layer-1 progress reset
}

// --------------------------- prep kernels ----------------------------------
__global__ void cvt_w_kernel(const void* __restrict__ in, f16* __restrict__ out,
                             int n, const int* __restrict__ dtf) {
    int dt = *dtf;
    for (int i = blockIdx.x * blockDim.x + threadIdx.x; i < n; i += gridDim.x * blockDim.x)
        out[i] = (f16)loadf(in, i, dt);
}

__global__ void bias_kernel(const void* __restrict__ bi, const void* __restrict__ bh,
                            float* __restrict__ bias, const int* __restrict__ dtf) {
    int dt = *dtf;
    int i = blockIdx.x * blockDim.x + threadIdx.x;
    if (i < H_DIM) bias[i] = loadf(bi, i, dt) + loadf(bh, i, dt);
}

__global__ void fcb_kernel(const void* __restrict__ in, float* __restrict__ out,
                           const int* __restrict__ dtf) {
    int i = threadIdx.x;
    if (i < 128) out[i] = loadf(in, i, *dtf);
}

// --------------------------- tiled MFMA GEMM -------------------------------
template<int RAW>
__global__ __launch_bounds__(256)
void gemm_tiled(const void* __restrict__ Araw, const f16* __restrict__ Bw,
                const float* __restrict__ bias, f16* __restrict__ C,
                int lgTc, int t_off, int K, const int* __restrict__ dtf)
{
    __shared__ f16 As[64][40];
    __shared__ f16 Bs[64][40];
    const int dt = RAW ? *dtf : 0;
    const int m0 = blockIdx.x * 64, n0 = blockIdx.y * 64;
    const int tid = threadIdx.x;
    const int wv = tid >> 6, lane = tid & 63;
    const int lr = lane & 15, quad = lane >> 4;
    const int srow = tid >> 2, skq = tid & 3;

    float4v acc[4] = {{0.f,0.f,0.f,0.f},{0.f,0.f,0.f,0.f},{0.f,0.f,0.f,0.f},{0.f,0.f,0.f,0.f}};

    size_t arow;
    {
        int ml = m0 + srow;
        if (RAW) {
            int b = ml >> lgTc, tt = ml & ((1 << lgTc) - 1);
            arow = (size_t)b * T_LEN + t_off + tt;
        } else arow = (size_t)ml;
    }
    const f16* pb = Bw + (size_t)(n0 + srow) * K + skq * 8;

    for (int k0 = 0; k0 < K; k0 += 32) {
        half8 av;
        if (RAW) {
            if (dt) {
                const float* ap = (const float*)Araw + arow * K + k0 + skq * 8;
                float4v f0 = *(const float4v*)ap;
                float4v f1 = *(const float4v*)(ap + 4);
                av[0]=(f16)f0[0]; av[1]=(f16)f0[1]; av[2]=(f16)f0[2]; av[3]=(f16)f0[3];
                av[4]=(f16)f1[0]; av[5]=(f16)f1[1]; av[6]=(f16)f1[2]; av[7]=(f16)f1[3];
            } else {
                av = cvt8_bf16(*(const uint4*)((const u16*)Araw + arow * K + k0 + skq * 8));
            }
        } else {
            av = *(const half8*)((const f16*)Araw + arow * K + k0 + skq * 8);
        }
        half8 bv = *(const half8*)(pb + k0);
        __syncthreads();
        *(half8*)&As[srow][skq * 8] = av;
        *(half8*)&Bs[srow][skq * 8] = bv;
        __syncthreads();
        half8 bf = *(const half8*)&Bs[wv * 16 + lr][quad * 8];
#pragma unroll
        for (int mt = 0; mt < 4; ++mt) {
            half8 af = *(const half8*)&As[mt * 16 + lr][quad * 8];
            acc[mt] = __builtin_amdgcn_mfma_f32_16x16x32_f16(af, bf, acc[mt], 0, 0, 0);
        }
    }
    const int n = n0 + wv * 16 + lr;
    const float bval = bias[n];
#pragma unroll
    for (int mt = 0; mt < 4; ++mt) {
#pragma unroll
        for (int i = 0; i < 4; ++i) {
            int m = m0 + mt * 16 + quad * 4 + i;
            C[(size_t)m * H_DIM + n] = (f16)(acc[mt][i] + bval);
        }
    }
}

// --------------------------- fused 2-layer scan ----------------------------
// grid = 32. bid<16: layer 0 (wid=bid); bid>=16: layer 1 (wid=bid-16).
// WG (r = wid>>2, cg = wid&3) -> batch rows [r*16,+16), cols [cg*128,+128).
// hex0: [4][64][128] u64 ring (slot t&3, 2-bit sign tag). hex1: [2][64][128].
// prog[16]: layer-1 WG wid stores t+1 after consuming h0_t; layer-0 blocks
// publish of t until prog >= t-LAG+1 (LAG=3 <= NBUF=4).
__global__ __launch_bounds__(256, 1)
void rnn_fused_scan(const f16* __restrict__ pre0,    // [B,Tc,H] chunk-local
                    const f16* __restrict__ Whh0,    // [H,H] fp16
                    const f16* __restrict__ Wih1,    // [H,H] fp16
                    const f16* __restrict__ Whh1,    // [H,H] fp16
                    const float* __restrict__ bias1, // [H] fp32
                    u64* __restrict__ hex0,          // [4][64][128]
                    u64* __restrict__ hex1,          // [2][64][128]
                    f16* __restrict__ hc0,           // [B,H] layer-0 carry
                    f16* __restrict__ hc1,           // [B,H] layer-1 carry
                    u32* __restrict__ prog,          // [16]
                    int t0, int Tc,
                    float* __restrict__ h_last)      // [B,H] fp32
{
    __shared__ f16 stage[2][16 * 512];   // h double buffer (granule-XOR swizzle)
    __shared__ f16 sH0[16 * 512];        // layer-1 only: h0_t staging
    const int bid = blockIdx.x;
    const int layer = bid >> 4;
    const int wid = bid & 15;
    const int r = wid >> 2, cg = wid & 3;
    const int rows0 = r * 16;
    const int tid = threadIdx.x;
    const int w = tid >> 6, lane = tid & 63;
    const int lr = lane & 15, quad = lane >> 4;
    const int c0w = cg * 128 + w * 32;
    // Remote-read assignment: thread covers u64-cols [rc8, rc8+8) of row rrow.
    const int rrow = tid >> 4;
    const int rc8 = (tid & 15) * 8;
    const bool mine = ((tid & 15) >> 2) == cg;   // own-slice words -> skip spin

    if (layer == 0) {
        // ================= layer 0 (scan + throttle) =================
        half8 Bf[2][16];
#pragma unroll
        for (int j = 0; j < 2; ++j)
#pragma unroll
            for (int kc = 0; kc < 16; ++kc)
                Bf[j][kc] = *(const half8*)(Whh0 + (size_t)(c0w + j * 16 + lr) * H_DIM
                                            + kc * 32 + quad * 8);

        if (t0 > 0) {
            int row = tid >> 4, g0 = (tid & 15) * 4;
#pragma unroll
            for (int gq = 0; gq < 4; ++gq) {
                int g = g0 + gq;
                *(uint4*)&stage[(t0 - 1) & 1][row * 512 + ((g ^ (row & 7)) * 8)] =
                    *(const uint4*)(hc0 + (size_t)(rows0 + row) * H_DIM + g * 8);
            }
        }
        __syncthreads();

        for (int tt = 0; tt < Tc; ++tt) {
            const int t = t0 + tt;
            const int p = (t - 1) & 1, np = t & 1;
            const int nb = t & 3;              // hex0 ring slot
            const u64 em = tagmask(t);
            const int need = t - LAG;
            const u32 want = (u32)(need + 1);

            // Early-issue throttle poll (latency hides under pv load + MFMA).
            u32 pvv = 0xffffffffu;
            if (need >= 0 && lane < 4)
                pvv = __hip_atomic_load(&prog[r * 4 + lane], __ATOMIC_RELAXED,
                                        __HIP_MEMORY_SCOPE_AGENT);

            // Prefetch pre_t (independent of the h chain).
            float pv[2][4];
#pragma unroll
            for (int j = 0; j < 2; ++j)
#pragma unroll
                for (int i = 0; i < 4; ++i)
                    pv[j][i] = (float)pre0[((size_t)(rows0 + quad * 4 + i) * Tc + tt) * H_DIM
                                           + c0w + j * 16 + lr];

            float4v acc0 = {0.f,0.f,0.f,0.f}, acc1 = {0.f,0.f,0.f,0.f};
            if (t > 0) {
                const f16* sb = stage[p];
#pragma unroll
                for (int kc = 0; kc < 16; ++kc) {
                    half8 a = *(const half8*)&sb[lr * 512 + (((kc * 4 + quad) ^ (lr & 7)) * 8)];
                    acc0 = __builtin_amdgcn_mfma_f32_16x16x32_f16(a, Bf[0][kc], acc0, 0, 0, 0);
                    acc1 = __builtin_amdgcn_mfma_f32_16x16x32_f16(a, Bf[1][kc], acc1, 0, 0, 0);
                }
            }

            // Compute h_t slice; write own values (untagged) into stage[np].
            f16* sw = stage[np];
            f16 hv16[2][4];
#pragma unroll
            for (int j = 0; j < 2; ++j) {
                const float4v& a = j ? acc1 : acc0;
#pragma unroll
                for (int i = 0; i < 4; ++i) {
                    float hval = fmaxf(a[i] + pv[j][i], 0.f);
                    hv16[j][i] = (f16)hval;
                    int row = quad * 4 + i, lc = c0w + j * 16 + lr;
                    sw[row * 512 + ((lc >> 3) ^ (row & 7)) * 8 + (lc & 7)] = hv16[j][i];
                }
            }
            if (tt == Tc - 1) {
#pragma unroll
                for (int j = 0; j < 2; ++j)
#pragma unroll
                    for (int i = 0; i < 4; ++i)
                        hc0[(size_t)(rows0 + quad * 4 + i) * H_DIM + c0w + j * 16 + lr] =
                            hv16[j][i];
            }
            __syncthreads();   // own-slice stage writes visible to publishers

            // Throttle resolve (per-wave). Publishing t destroys ring slot of
            // step t-4; LAG=3 certifies layer-1 consumed t-3 -> slot is dead.
            if (need >= 0) {
                bool ok = __all((lane < 4) ? (pvv >= want) : 1);
                int g = 0;
                while (!ok && g < SPIN_LIM) {
                    if (lane < 4)
                        pvv = __hip_atomic_load(&prog[r * 4 + lane], __ATOMIC_RELAXED,
                                                __HIP_MEMORY_SCOPE_AGENT);
                    ok = __all((lane < 4) ? (pvv >= want) : 1);
                    ++g;
                }
            }

            // Publish own 2 u64 (tagged) via agent-scope atomic stores.
            {
                int row = tid >> 4, poc = (tid & 15) * 2, cu = cg * 32 + poc;
                uint4 q4 = *(const uint4*)&stage[np][row * 512 + (((cu >> 1) ^ (row & 7)) * 8)];
                u64 v0 = (((u64)q4.y) << 32) | q4.x;
                u64 v1 = (((u64)q4.w) << 32) | q4.z;
                u64* dst = hex0 + ((size_t)nb * 64 + rows0 + row) * 128;
                astore(&dst[cu], v0 | em);
                astore(&dst[cu + 1], v1 | em);
            }

            // Spin-read the 3 sibling slices (tag-validated), into stage[np].
            if (!mine) {
                u64* src = hex0 + ((size_t)nb * 64 + rows0 + rrow) * 128;
                u64 vv[8];
                int pend = 0xff, guard = 0;
                while (pend && guard < SPIN_LIM) {
#pragma unroll
                    for (int q = 0; q < 8; ++q)
                        if (pend & (1 << q)) vv[q] = aload(&src[rc8 + q]);
#pragma unroll
                    for (int q = 0; q < 8; ++q)
                        if ((pend & (1 << q)) && ((vv[q] & SGN) == em))
                            pend &= ~(1 << q);
                    ++guard;
                }
#pragma unroll
                for (int q = 0; q < 8; ++q) {
                    int cu = rc8 + q;
                    *(u64*)&stage[np][rrow * 512 + ((cu >> 1) ^ (rrow & 7)) * 8 + (cu & 1) * 4] =
                        vv[q] & VMASK;
                }
            }
            __syncthreads();   // stage[np] complete for step t+1
        }
    } else {
        // ================= layer 1 (fused input-proj + recurrence) ===========
        half8 BfI[2][16], BfH[2][16];
#pragma unroll
        for (int j = 0; j < 2; ++j)
#pragma unroll
            for (int kc = 0; kc < 16; ++kc) {
                BfI[j][kc] = *(const half8*)(Wih1 + (size_t)(c0w + j * 16 + lr) * H_DIM
                                             + kc * 32 + quad * 8);
                BfH[j][kc] = *(const half8*)(Whh1 + (size_t)(c0w + j * 16 + lr) * H_DIM
                                             + kc * 32 + quad * 8);
            }
        float bvv[2] = { bias1[c0w + lr], bias1[c0w + 16 + lr] };

        if (t0 > 0) {
            int row = tid >> 4, g0 = (tid & 15) * 4;
#pragma unroll
            for (int gq = 0; gq < 4; ++gq) {
                int g = g0 + gq;
                *(uint4*)&stage[(t0 - 1) & 1][row * 512 + ((g ^ (row & 7)) * 8)] =
                    *(const uint4*)(hc1 + (size_t)(rows0 + row) * H_DIM + g * 8);
            }
        }
        __syncthreads();

        // Prefetch h0_{t0}: issue the 8 u64 loads now (validated in-loop).
        u64 vv[8];
        {
            u64* src = hex0 + ((size_t)(t0 & 3) * 64 + rows0 + rrow) * 128;
#pragma unroll
            for (int q = 0; q < 8; ++q) vv[q] = aload(&src[rc8 + q]);
        }

        for (int tt = 0; tt < Tc; ++tt) {
            const int t = t0 + tt;
            const int p = (t - 1) & 1, np = t & 1;
            const int nb = t & 3;              // hex0 ring slot
            const u64 em = tagmask(t);

            // 1. Complete h0_t from prefetched vv (tag-validate, reload pend).
            {
                u64* src = hex0 + ((size_t)nb * 64 + rows0 + rrow) * 128;
                int pend = 0;
#pragma unroll
                for (int q = 0; q < 8; ++q)
                    if ((vv[q] & SGN) != em) pend |= 1 << q;
                int guard = 0;
                while (pend && guard < SPIN_LIM) {
#pragma unroll
                    for (int q = 0; q < 8; ++q)
                        if (pend & (1 << q)) vv[q] = aload(&src[rc8 + q]);
#pragma unroll
                    for (int q = 0; q < 8; ++q)
                        if ((pend & (1 << q)) && ((vv[q] & SGN) == em))
                            pend &= ~(1 << q);
                    ++guard;
                }
#pragma unroll
                for (int q = 0; q < 8; ++q) {
                    int cu = rc8 + q;
                    *(u64*)&sH0[rrow * 512 + ((cu >> 1) ^ (rrow & 7)) * 8 + (cu & 1) * 4] =
                        vv[q] & VMASK;
                }
            }
            __syncthreads();   // sH0 complete; all hex0[t] reads done

            // 2. Report consumption of h0_t (unblocks layer-0's step t+LAG).
            if (tid == 0)
                __hip_atomic_store(&prog[wid], (u32)(t + 1), __ATOMIC_RELAXED,
                                   __HIP_MEMORY_SCOPE_AGENT);

            // 3. Fused K=1024 MFMA chain: h0_t @ Wih1^T + h1_{t-1} @ Whh1^T.
            float4v acc0 = {0.f,0.f,0.f,0.f}, acc1 = {0.f,0.f,0.f,0.f};
#pragma unroll
            for (int kc = 0; kc < 16; ++kc) {
                half8 a = *(const half8*)&sH0[lr * 512 + (((kc * 4 + quad) ^ (lr & 7)) * 8)];
                acc0 = __builtin_amdgcn_mfma_f32_16x16x32_f16(a, BfI[0][kc], acc0, 0, 0, 0);
                acc1 = __builtin_amdgcn_mfma_f32_16x16x32_f16(a, BfI[1][kc], acc1, 0, 0, 0);
            }
            if (t > 0) {
                const f16* sb = stage[p];
#pragma unroll
                for (int kc = 0; kc < 16; ++kc) {
                    half8 a = *(const half8*)&sb[lr * 512 + (((kc * 4 + quad) ^ (lr & 7)) * 8)];
                    acc0 = __builtin_amdgcn_mfma_f32_16x16x32_f16(a, BfH[0][kc], acc0, 0, 0, 0);
                    acc1 = __builtin_amdgcn_mfma_f32_16x16x32_f16(a, BfH[1][kc], acc1, 0, 0, 0);
                }
            }

            // 3b. Issue prefetch of h0_{t+1} (in flight across stage/publish/
            // sibling phases; validated at top of next iteration).
            if (tt + 1 < Tc) {
                u64* srcn = hex0 + ((size_t)((t + 1) & 3) * 64 + rows0 + rrow) * 128;
#pragma unroll
                for (int q = 0; q < 8; ++q) vv[q] = aload(&srcn[rc8 + q]);
            }

            // 4. h1_t = relu(acc + bias1); write own slice into stage[np].
            f16* sw = stage[np];
            f16 hv16[2][4];
#pragma unroll
            for (int j = 0; j < 2; ++j) {
                const float4v& a = j ? acc1 : acc0;
#pragma unroll
                for (int i = 0; i < 4; ++i) {
                    float hval = fmaxf(a[i] + bvv[j], 0.f);
                    hv16[j][i] = (f16)hval;
                    int row = quad * 4 + i, lc = c0w + j * 16 + lr;
                    sw[row * 512 + ((lc >> 3) ^ (row & 7)) * 8 + (lc & 7)] = hv16[j][i];
                }
            }
            if (h_last && t == T_LEN - 1) {
#pragma unroll
                for (int j = 0; j < 2; ++j)
#pragma unroll
                    for (int i = 0; i < 4; ++i)
                        h_last[(size_t)(rows0 + quad * 4 + i) * H_DIM + c0w + j * 16 + lr] =
                            (float)hv16[j][i];
            }
            if (tt == Tc - 1) {
#pragma unroll
                for (int j = 0; j < 2; ++j)
#pragma unroll
                    for (int i = 0; i < 4; ++i)
                        hc1[(size_t)(rows0 + quad * 4 + i) * H_DIM + c0w + j * 16 + lr] =
                            hv16[j][i];
            }
            __syncthreads();   // own-slice stage writes visible to publishers

            // 5. Publish own 2 u64 (tagged) to hex1 via atomic stores.
            {
                int row = tid >> 4, poc = (tid & 15) * 2, cu = cg * 32 + poc;
                uint4 q4 = *(const uint4*)&stage[np][row * 512 + (((cu >> 1) ^ (row & 7)) * 8)];
                u64 v0 = (((u64)q4.y) << 32) | q4.x;
                u64 v1 = (((u64)q4.w) << 32) | q4.z;
                u64* dst = hex1 + ((size_t)np * 64 + rows0 + row) * 128;
                astore(&dst[cu], v0 | em);
                astore(&dst[cu + 1], v1 | em);
            }

            // 6. Spin-read sibling h1 slices -> stage[np].
            if (!mine) {
                u64* src = hex1 + ((size_t)np * 64 + rows0 + rrow) * 128;
                u64 sv[8];
                int pend = 0xff, guard = 0;
                while (pend && guard < SPIN_LIM) {
#pragma unroll
                    for (int q = 0; q < 8; ++q)
                        if (pend & (1 << q)) sv[q] = aload(&src[rc8 + q]);
#pragma unroll
                    for (int q = 0; q < 8; ++q)
                        if ((pend & (1 << q)) && ((sv[q] & SGN) == em))
                            pend &= ~(1 << q);
                    ++guard;
                }
#pragma unroll
                for (int q = 0; q < 8; ++q) {
                    int cu = rc8 + q;
                    *(u64*)&stage[np][rrow * 512 + ((cu >> 1) ^ (rrow & 7)) * 8 + (cu & 1) * 4] =
                        sv[q] & VMASK;
                }
            }
            __syncthreads();   // stage[np] complete for step t+1
        }
    }
}

// --------------------------- final FC --------------------------------------
__global__ void fc_kernel(const float* __restrict__ hlast, const f16* __restrict__ fcw,
                          const float* __restrict__ fcb, void* __restrict__ out,
                          const int* __restrict__ dtf) {
    int b = blockIdx.x, c = threadIdx.x;
    const float* hrow = hlast + b * H_DIM;
    const f16* wrow = fcw + (size_t)c * H_DIM;
    float s = fcb[c];
    for (int h0 = 0; h0 < H_DIM; h0 += 8) {
        half8 w = *(const half8*)(wrow + h0);
#pragma unroll
        for (int j = 0; j < 8; ++j) s += hrow[h0 + j] * (float)w[j];
    }
    if (*dtf) ((float*)out)[b * 128 + c] = s;
    else      ((u16*)out)[b * 128 + c] = f2bf(s);
}

// --------------------------- launch ----------------------------------------
extern "C" void kernel_launch(void* const* d_in, const int* in_sizes, int n_in,
                              void* d_out, int out_size, void* d_ws, size_t ws_size,
                              hipStream_t stream)
{
    const void* x     = d_in[0];
    const void* W_ih0 = d_in[1];
    const void* W_hh0 = d_in[2];
    const void* b_ih0 = d_in[3];
    const void* b_hh0 = d_in[4];
    const void* W_ih1 = d_in[5];
    const void* W_hh1 = d_in[6];
    const void* b_ih1 = d_in[7];
    const void* b_hh1 = d_in[8];
    const void* fc_w  = d_in[9];
    const void* fc_b  = d_in[10];

    char* ws = (char*)d_ws;
    int*   dtf   = (int*)(ws + 0);            //     64 B
    float* bias0 = (float*)(ws + 4096);       //   2048 B
    float* bias1 = (float*)(ws + 6144);       //   2048 B
    float* fcbf  = (float*)(ws + 8192);       //    512 B
    u32*   prog  = (u32*)(ws + 12288);        //     64 B
    float* hlast = (float*)(ws + 16384);      // 131072 B
    f16*   hc0   = (f16*)(ws + 147456);       //  65536 B
    f16*   hc1   = (f16*)(ws + 212992);       //  65536 B
    u64*   hex0  = (u64*)(ws + 278528);       // 262144 B [4][64][128] u64 ring
    u64*   hex1  = (u64*)(ws + 540672);       // 131072 B [2][64][128]
    f16*   Wih0f = (f16*)(ws + 671744);       // 262144 B
    f16*   Whh0f = (f16*)(ws + 933888);       // 524288 B
    f16*   Wih1f = (f16*)(ws + 1458176);      // 524288 B
    f16*   Whh1f = (f16*)(ws + 1982464);      // 524288 B
    f16*   fcwf  = (f16*)(ws + 2506752);      // 131072 B

    const size_t misc = 4u << 20;
    int Tc = 128;
    {
        auto need = [&](int tc) {
            return misc + (size_t)B_SZ * (size_t)tc * H_DIM * 2;   // single buffer
        };
        if (ws_size >= need(2048)) Tc = 2048;
        else if (ws_size >= need(1024)) Tc = 1024;
        else if (ws_size >= need(512)) Tc = 512;
        else if (ws_size >= need(256)) Tc = 256;
        else Tc = 128;
    }
    int lgTc = 31 - __builtin_clz((unsigned)Tc);
    f16* bufA = (f16*)(ws + misc);

    detect_kernel<<<dim3(1), dim3(64), 0, stream>>>((const u16*)x, dtf, prog);
    cvt_w_kernel<<<dim3(512), dim3(256), 0, stream>>>(W_ih0, Wih0f, H_DIM * 256, dtf);
    cvt_w_kernel<<<dim3(1024), dim3(256), 0, stream>>>(W_hh0, Whh0f, H_DIM * H_DIM, dtf);
    cvt_w_kernel<<<dim3(1024), dim3(256), 0, stream>>>(W_ih1, Wih1f, H_DIM * H_DIM, dtf);
    cvt_w_kernel<<<dim3(1024), dim3(256), 0, stream>>>(W_hh1, Whh1f, H_DIM * H_DIM, dtf);
    cvt_w_kernel<<<dim3(256), dim3(256), 0, stream>>>(fc_w, fcwf, 128 * H_DIM, dtf);
    bias_kernel<<<dim3(2), dim3(256), 0, stream>>>(b_ih0, b_hh0, bias0, dtf);
    bias_kernel<<<dim3(2), dim3(256), 0, stream>>>(b_ih1, b_hh1, bias1, dtf);
    fcb_kernel<<<dim3(1), dim3(128), 0, stream>>>(fc_b, fcbf, dtf);

    const int NC = T_LEN / Tc;
    const int mblocks = B_SZ * Tc / 64;
    for (int c = 0; c < NC; ++c) {
        const int t0 = c * Tc;
        gemm_tiled<1><<<dim3(mblocks, 8), 256, 0, stream>>>(
            x, Wih0f, bias0, bufA, lgTc, t0, 256, dtf);
        rnn_fused_scan<<<dim3(32), 256, 0, stream>>>(
            bufA, Whh0f, Wih1f, Whh1f, bias1, hex0, hex1, hc0, hc1, prog,
            t0, Tc, hlast);
    }
    fc_kernel<<<dim3(B_SZ), dim3(128), 0, stream>>>(hlast, fcwf, fcbf, d_out, dtf);
}

// Round 4
// 9293.983 us; speedup vs baseline: 1.1632x; 1.1014x over previous
//
#include <hip/hip_runtime.h>

// ---------------------------------------------------------------------------
// 2-layer ReLU RNN, B=64 T=2048 IN=256 H=512 C=128. fp32 inputs (runtime
// dtype detect kept), output dtype matches input.
//
// Round-9: remove the prog round-trip from the steady-state loop and
// deferred-validate ALL exchange reads.
//  (1) hex0 ring deepened to 8 (slot t&7), LAG=7, 4-bit step tag (t&15, one
//      bit per f16 sign; u64 atomics -> no tearing). prog RT amortizes over
//      7 steps; layer-0 leads up to 7 -> layer-1's h0 prefetch always hits.
//      Alias audit: same-slot distance 8 flips tag bit3; replay residue
//      (old tags 8..15 in slots 0..7) never matches new tags 0..7; 0xAA
//      poison = tag 15, slot 7 rewritten at t=7 before first use at t=15.
//  (2) Sibling exchange (both layers) is issue-early/validate-late like the
//      h0 prefetch: 8 u64 loads issued right after publish, tag-validated
//      at the top of the next step (spin only on miss).
//  (3) Layer-0 pre0 (pv) loads software-pipelined one step ahead.
// All spins guard-limited -> no hangs, worst case wrong data (caught by
// absmax).
// ---------------------------------------------------------------------------

typedef unsigned short u16;
typedef unsigned int u32;
typedef unsigned long long u64;
typedef _Float16 f16;
typedef _Float16 half8 __attribute__((ext_vector_type(8)));
typedef float float4v __attribute__((ext_vector_type(4)));

#define T_LEN 2048
#define H_DIM 512
#define B_SZ 64
#define SGN 0x8000800080008000ull
#define VMASK 0x7fff7fff7fff7fffull
#define SPIN_LIM (1 << 15)
#define LAG 7

__device__ __forceinline__ float bf2f(u16 u) {
    union { u32 i; float f; } v; v.i = ((u32)u) << 16; return v.f;
}
__device__ __forceinline__ u16 f2bf(float f) {
    u32 x = __float_as_uint(f);
    u32 r = (x + 0x7fffu + ((x >> 16) & 1u)) >> 16;
    return (u16)r;
}
__device__ __forceinline__ float loadf(const void* p, size_t i, int dt) {
    return dt ? ((const float*)p)[i] : bf2f(((const u16*)p)[i]);
}
__device__ __forceinline__ half8 cvt8_bf16(uint4 v) {
    half8 h;
    h[0] = (f16)bf2f((u16)(v.x & 0xffff)); h[1] = (f16)bf2f((u16)(v.x >> 16));
    h[2] = (f16)bf2f((u16)(v.y & 0xffff)); h[3] = (f16)bf2f((u16)(v.y >> 16));
    h[4] = (f16)bf2f((u16)(v.z & 0xffff)); h[5] = (f16)bf2f((u16)(v.z >> 16));
    h[6] = (f16)bf2f((u16)(v.w & 0xffff)); h[7] = (f16)bf2f((u16)(v.w >> 16));
    return h;
}
// 4-bit tag (t & 15) in the 4 f16 sign bits of a u64.
__device__ __forceinline__ u64 tagmask(int t) {
    return ((t & 1) ? 0x0000000000008000ull : 0ull) |
           ((t & 2) ? 0x0000000080000000ull : 0ull) |
           ((t & 4) ? 0x0000800000000000ull : 0ull) |
           ((t & 8) ? 0x8000000000000000ull : 0ull);
}
__device__ __forceinline__ u64 aload(u64* p) {
    return __hip_atomic_load(p, __ATOMIC_RELAXED, __HIP_MEMORY_SCOPE_AGENT);
}
__device__ __forceinline__ void astore(u64* p, u64 v) {
    __hip_atomic_store(p, v, __ATOMIC_RELAXED, __HIP_MEMORY_SCOPE_AGENT);
}
// Validate 8 in-flight words against tag em; spin-reload misses from src[rc8+q].
__device__ __forceinline__ void validate8(u64* src, int rc8, u64 em, u64* vv) {
    int pend = 0;
#pragma unroll
    for (int q = 0; q < 8; ++q)
        if ((vv[q] & SGN) != em) pend |= 1 << q;
    int guard = 0;
    while (pend && guard < SPIN_LIM) {
#pragma unroll
        for (int q = 0; q < 8; ++q)
            if (pend & (1 << q)) vv[q] = aload(&src[rc8 + q]);
#pragma unroll
        for (int q = 0; q < 8; ++q)
            if ((pend & (1 << q)) && ((vv[q] & SGN) == em))
                pend &= ~(1 << q);
        ++guard;
    }
}

// --------------------------- dtype detection -------------------------------
__global__ void detect_kernel(const u16* __restrict__ xr, int* __restrict__ dtf,
                              u32* __restrict__ prog) {
    int lane = threadIdx.x;
    u16 u0 = xr[(lane * 2 + 0) * 2];
    u16 u1 = xr[(lane * 2 + 1) * 2];
    int e0 = (u0 >> 7) & 0xff, e1 = (u1 >> 7) & 0xff;
    int c0 = (e0 >= 0x60 && e0 <= 0x8f) ? 1 : 0;
    int c1 = (e1 >= 0x60 && e1 <= 0x8f) ? 1 : 0;
    int tot = __popcll(__ballot(c0)) + __popcll(__ballot(c1));
    if (lane == 0) *dtf = (tot >= 96) ? 0 : 1;   // 0 = bf16, 1 = fp32
    if (lane < 16) prog[lane] = 0;               // layer-1 progress reset
}

// --------------------------- prep kernels ----------------------------------
__global__ void cvt_w_kernel(const void* __restrict__ in, f16* __restrict__ out,
                             int n, const int* __restrict__ dtf) {
    int dt = *dtf;
    for (int i = blockIdx.x * blockDim.x + threadIdx.x; i < n; i += gridDim.x * blockDim.x)
        out[i] = (f16)loadf(in, i, dt);
}

__global__ void bias_kernel(const void* __restrict__ bi, const void* __restrict__ bh,
                            float* __restrict__ bias, const int* __restrict__ dtf) {
    int dt = *dtf;
    int i = blockIdx.x * blockDim.x + threadIdx.x;
    if (i < H_DIM) bias[i] = loadf(bi, i, dt) + loadf(bh, i, dt);
}

__global__ void fcb_kernel(const void* __restrict__ in, float* __restrict__ out,
                           const int* __restrict__ dtf) {
    int i = threadIdx.x;
    if (i < 128) out[i] = loadf(in, i, *dtf);
}

// --------------------------- tiled MFMA GEMM -------------------------------
template<int RAW>
__global__ __launch_bounds__(256)
void gemm_tiled(const void* __restrict__ Araw, const f16* __restrict__ Bw,
                const float* __restrict__ bias, f16* __restrict__ C,
                int lgTc, int t_off, int K, const int* __restrict__ dtf)
{
    __shared__ f16 As[64][40];
    __shared__ f16 Bs[64][40];
    const int dt = RAW ? *dtf : 0;
    const int m0 = blockIdx.x * 64, n0 = blockIdx.y * 64;
    const int tid = threadIdx.x;
    const int wv = tid >> 6, lane = tid & 63;
    const int lr = lane & 15, quad = lane >> 4;
    const int srow = tid >> 2, skq = tid & 3;

    float4v acc[4] = {{0.f,0.f,0.f,0.f},{0.f,0.f,0.f,0.f},{0.f,0.f,0.f,0.f},{0.f,0.f,0.f,0.f}};

    size_t arow;
    {
        int ml = m0 + srow;
        if (RAW) {
            int b = ml >> lgTc, tt = ml & ((1 << lgTc) - 1);
            arow = (size_t)b * T_LEN + t_off + tt;
        } else arow = (size_t)ml;
    }
    const f16* pb = Bw + (size_t)(n0 + srow) * K + skq * 8;

    for (int k0 = 0; k0 < K; k0 += 32) {
        half8 av;
        if (RAW) {
            if (dt) {
                const float* ap = (const float*)Araw + arow * K + k0 + skq * 8;
                float4v f0 = *(const float4v*)ap;
                float4v f1 = *(const float4v*)(ap + 4);
                av[0]=(f16)f0[0]; av[1]=(f16)f0[1]; av[2]=(f16)f0[2]; av[3]=(f16)f0[3];
                av[4]=(f16)f1[0]; av[5]=(f16)f1[1]; av[6]=(f16)f1[2]; av[7]=(f16)f1[3];
            } else {
                av = cvt8_bf16(*(const uint4*)((const u16*)Araw + arow * K + k0 + skq * 8));
            }
        } else {
            av = *(const half8*)((const f16*)Araw + arow * K + k0 + skq * 8);
        }
        half8 bv = *(const half8*)(pb + k0);
        __syncthreads();
        *(half8*)&As[srow][skq * 8] = av;
        *(half8*)&Bs[srow][skq * 8] = bv;
        __syncthreads();
        half8 bf = *(const half8*)&Bs[wv * 16 + lr][quad * 8];
#pragma unroll
        for (int mt = 0; mt < 4; ++mt) {
            half8 af = *(const half8*)&As[mt * 16 + lr][quad * 8];
            acc[mt] = __builtin_amdgcn_mfma_f32_16x16x32_f16(af, bf, acc[mt], 0, 0, 0);
        }
    }
    const int n = n0 + wv * 16 + lr;
    const float bval = bias[n];
#pragma unroll
    for (int mt = 0; mt < 4; ++mt) {
#pragma unroll
        for (int i = 0; i < 4; ++i) {
            int m = m0 + mt * 16 + quad * 4 + i;
            C[(size_t)m * H_DIM + n] = (f16)(acc[mt][i] + bval);
        }
    }
}

// --------------------------- fused 2-layer scan ----------------------------
// grid = 32. bid<16: layer 0 (wid=bid); bid>=16: layer 1 (wid=bid-16).
// WG (r = wid>>2, cg = wid&3) -> batch rows [r*16,+16), cols [cg*128,+128).
// hex0: [8][64][128] u64 ring (slot t&7, 4-bit sign tag t&15).
// hex1: [2][64][128] (slot t&1). prog[16]: layer-1 WG wid stores t+1 after
// consuming h0_t; layer-0 blocks publish of t until prog >= t-LAG+1
// (LAG=7 = NBUF-1).
__global__ __launch_bounds__(256, 1)
void rnn_fused_scan(const f16* __restrict__ pre0,    // [B,Tc,H] chunk-local
                    const f16* __restrict__ Whh0,    // [H,H] fp16
                    const f16* __restrict__ Wih1,    // [H,H] fp16
                    const f16* __restrict__ Whh1,    // [H,H] fp16
                    const float* __restrict__ bias1, // [H] fp32
                    u64* __restrict__ hex0,          // [8][64][128]
                    u64* __restrict__ hex1,          // [2][64][128]
                    f16* __restrict__ hc0,           // [B,H] layer-0 carry
                    f16* __restrict__ hc1,           // [B,H] layer-1 carry
                    u32* __restrict__ prog,          // [16]
                    int t0, int Tc,
                    float* __restrict__ h_last)      // [B,H] fp32
{
    __shared__ f16 stage[2][16 * 512];   // h double buffer (granule-XOR swizzle)
    __shared__ f16 sH0[16 * 512];        // layer-1 only: h0_t staging
    const int bid = blockIdx.x;
    const int layer = bid >> 4;
    const int wid = bid & 15;
    const int r = wid >> 2, cg = wid & 3;
    const int rows0 = r * 16;
    const int tid = threadIdx.x;
    const int w = tid >> 6, lane = tid & 63;
    const int lr = lane & 15, quad = lane >> 4;
    const int c0w = cg * 128 + w * 32;
    // Remote-read assignment: thread covers u64-cols [rc8, rc8+8) of row rrow.
    const int rrow = tid >> 4;
    const int rc8 = (tid & 15) * 8;
    const bool mine = ((tid & 15) >> 2) == cg;   // own-slice words -> skip spin

    if (layer == 0) {
        // ================= layer 0 =================
        half8 Bf[2][16];
#pragma unroll
        for (int j = 0; j < 2; ++j)
#pragma unroll
            for (int kc = 0; kc < 16; ++kc)
                Bf[j][kc] = *(const half8*)(Whh0 + (size_t)(c0w + j * 16 + lr) * H_DIM
                                            + kc * 32 + quad * 8);

        if (t0 > 0) {
            int row = tid >> 4, g0 = (tid & 15) * 4;
#pragma unroll
            for (int gq = 0; gq < 4; ++gq) {
                int g = g0 + gq;
                *(uint4*)&stage[(t0 - 1) & 1][row * 512 + ((g ^ (row & 7)) * 8)] =
                    *(const uint4*)(hc0 + (size_t)(rows0 + row) * H_DIM + g * 8);
            }
        }
        __syncthreads();

        u64 sv[8];                       // in-flight sibling words, step t-1
        float pv[2][4];                  // pre_t, pipelined one step ahead
#pragma unroll
        for (int j = 0; j < 2; ++j)
#pragma unroll
            for (int i = 0; i < 4; ++i)
                pv[j][i] = (float)pre0[((size_t)(rows0 + quad * 4 + i) * Tc + 0) * H_DIM
                                       + c0w + j * 16 + lr];

        for (int tt = 0; tt < Tc; ++tt) {
            const int t = t0 + tt;
            const int p = (t - 1) & 1, np = t & 1;
            const int nb = t & 7;              // hex0 ring slot
            const u64 em = tagmask(t);
            const int need = t - LAG;
            const u32 want = (u32)(need + 1);

            // Early-issue throttle poll.
            u32 pvv = 0xffffffffu;
            if (need >= 0 && lane < 4)
                pvv = __hip_atomic_load(&prog[r * 4 + lane], __ATOMIC_RELAXED,
                                        __HIP_MEMORY_SCOPE_AGENT);

            // [A] validate in-flight sibling words of step t-1 -> stage[p].
            if (tt > 0 && !mine) {
                u64* src = hex0 + ((size_t)((t - 1) & 7) * 64 + rows0 + rrow) * 128;
                validate8(src, rc8, tagmask(t - 1), sv);
#pragma unroll
                for (int q = 0; q < 8; ++q) {
                    int cu = rc8 + q;
                    *(u64*)&stage[p][rrow * 512 + ((cu >> 1) ^ (rrow & 7)) * 8 + (cu & 1) * 4] =
                        sv[q] & VMASK;
                }
            }
            __syncthreads();   // stage[p] complete

            // [D] Whh MFMA chain.
            float4v acc0 = {0.f,0.f,0.f,0.f}, acc1 = {0.f,0.f,0.f,0.f};
            if (t > 0) {
                const f16* sb = stage[p];
#pragma unroll
                for (int kc = 0; kc < 16; ++kc) {
                    half8 a = *(const half8*)&sb[lr * 512 + (((kc * 4 + quad) ^ (lr & 7)) * 8)];
                    acc0 = __builtin_amdgcn_mfma_f32_16x16x32_f16(a, Bf[0][kc], acc0, 0, 0, 0);
                    acc1 = __builtin_amdgcn_mfma_f32_16x16x32_f16(a, Bf[1][kc], acc1, 0, 0, 0);
                }
            }

            // [E] h_t = relu(acc + pv); own slice -> stage[np].
            f16* sw = stage[np];
            f16 hv16[2][4];
#pragma unroll
            for (int j = 0; j < 2; ++j) {
                const float4v& a = j ? acc1 : acc0;
#pragma unroll
                for (int i = 0; i < 4; ++i) {
                    float hval = fmaxf(a[i] + pv[j][i], 0.f);
                    hv16[j][i] = (f16)hval;
                    int row = quad * 4 + i, lc = c0w + j * 16 + lr;
                    sw[row * 512 + ((lc >> 3) ^ (row & 7)) * 8 + (lc & 7)] = hv16[j][i];
                }
            }
            if (tt == Tc - 1) {
#pragma unroll
                for (int j = 0; j < 2; ++j)
#pragma unroll
                    for (int i = 0; i < 4; ++i)
                        hc0[(size_t)(rows0 + quad * 4 + i) * H_DIM + c0w + j * 16 + lr] =
                            hv16[j][i];
            }
            __syncthreads();   // own-slice stage writes visible to publishers

            // Throttle resolve: publishing t destroys slot of t-8; LAG=7
            // certifies layer-1 consumed t-7 >= t-8.
            if (need >= 0) {
                bool ok = __all((lane < 4) ? (pvv >= want) : 1);
                int g = 0;
                while (!ok && g < SPIN_LIM) {
                    if (lane < 4)
                        pvv = __hip_atomic_load(&prog[r * 4 + lane], __ATOMIC_RELAXED,
                                                __HIP_MEMORY_SCOPE_AGENT);
                    ok = __all((lane < 4) ? (pvv >= want) : 1);
                    ++g;
                }
            }

            // [F] publish own 2 u64 (tagged); issue sibling loads for step t;
            // preload pv for step t+1.
            {
                int row = tid >> 4, poc = (tid & 15) * 2, cu = cg * 32 + poc;
                uint4 q4 = *(const uint4*)&stage[np][row * 512 + (((cu >> 1) ^ (row & 7)) * 8)];
                u64 v0 = (((u64)q4.y) << 32) | q4.x;
                u64 v1 = (((u64)q4.w) << 32) | q4.z;
                u64* dst = hex0 + ((size_t)nb * 64 + rows0 + row) * 128;
                astore(&dst[cu], v0 | em);
                astore(&dst[cu + 1], v1 | em);
            }
            if (!mine) {
                u64* src = hex0 + ((size_t)nb * 64 + rows0 + rrow) * 128;
#pragma unroll
                for (int q = 0; q < 8; ++q) sv[q] = aload(&src[rc8 + q]);
            }
            if (tt + 1 < Tc) {
#pragma unroll
                for (int j = 0; j < 2; ++j)
#pragma unroll
                    for (int i = 0; i < 4; ++i)
                        pv[j][i] = (float)pre0[((size_t)(rows0 + quad * 4 + i) * Tc + tt + 1)
                                               * H_DIM + c0w + j * 16 + lr];
            }
            // No trailing barrier: next [A] writes sibling cols (disjoint from
            // publisher reads of own cols); B1 of next iter orders before [D].
        }
    } else {
        // ================= layer 1 (fused input-proj + recurrence) ===========
        half8 BfI[2][16], BfH[2][16];
#pragma unroll
        for (int j = 0; j < 2; ++j)
#pragma unroll
            for (int kc = 0; kc < 16; ++kc) {
                BfI[j][kc] = *(const half8*)(Wih1 + (size_t)(c0w + j * 16 + lr) * H_DIM
                                             + kc * 32 + quad * 8);
                BfH[j][kc] = *(const half8*)(Whh1 + (size_t)(c0w + j * 16 + lr) * H_DIM
                                             + kc * 32 + quad * 8);
            }
        float bvv[2] = { bias1[c0w + lr], bias1[c0w + 16 + lr] };

        if (t0 > 0) {
            int row = tid >> 4, g0 = (tid & 15) * 4;
#pragma unroll
            for (int gq = 0; gq < 4; ++gq) {
                int g = g0 + gq;
                *(uint4*)&stage[(t0 - 1) & 1][row * 512 + ((g ^ (row & 7)) * 8)] =
                    *(const uint4*)(hc1 + (size_t)(rows0 + row) * H_DIM + g * 8);
            }
        }
        __syncthreads();

        u64 vv[8];                        // in-flight h0 words, step t
        u64 sv[8];                        // in-flight h1 sibling words, step t-1
        {
            u64* src = hex0 + ((size_t)(t0 & 7) * 64 + rows0 + rrow) * 128;
#pragma unroll
            for (int q = 0; q < 8; ++q) vv[q] = aload(&src[rc8 + q]);
        }

        for (int tt = 0; tt < Tc; ++tt) {
            const int t = t0 + tt;
            const int p = (t - 1) & 1, np = t & 1;
            const int nb = t & 7;              // hex0 ring slot
            const u64 em = tagmask(t);

            // [A] validate h0_t -> sH0.
            {
                u64* src = hex0 + ((size_t)nb * 64 + rows0 + rrow) * 128;
                validate8(src, rc8, em, vv);
#pragma unroll
                for (int q = 0; q < 8; ++q) {
                    int cu = rc8 + q;
                    *(u64*)&sH0[rrow * 512 + ((cu >> 1) ^ (rrow & 7)) * 8 + (cu & 1) * 4] =
                        vv[q] & VMASK;
                }
            }
            // [B] validate h1 sibling words of step t-1 -> stage[p].
            if (tt > 0 && !mine) {
                u64* src = hex1 + ((size_t)((t - 1) & 1) * 64 + rows0 + rrow) * 128;
                validate8(src, rc8, tagmask(t - 1), sv);
#pragma unroll
                for (int q = 0; q < 8; ++q) {
                    int cu = rc8 + q;
                    *(u64*)&stage[p][rrow * 512 + ((cu >> 1) ^ (rrow & 7)) * 8 + (cu & 1) * 4] =
                        sv[q] & VMASK;
                }
            }
            __syncthreads();   // sH0 + stage[p] complete; all slot-t reads done

            // [C] report consumption of h0_t (unblocks layer-0's t+LAG).
            if (tid == 0)
                __hip_atomic_store(&prog[wid], (u32)(t + 1), __ATOMIC_RELAXED,
                                   __HIP_MEMORY_SCOPE_AGENT);

            // [D] fused K=1024 chain: h0_t @ Wih1^T + h1_{t-1} @ Whh1^T.
            float4v acc0 = {0.f,0.f,0.f,0.f}, acc1 = {0.f,0.f,0.f,0.f};
#pragma unroll
            for (int kc = 0; kc < 16; ++kc) {
                half8 a = *(const half8*)&sH0[lr * 512 + (((kc * 4 + quad) ^ (lr & 7)) * 8)];
                acc0 = __builtin_amdgcn_mfma_f32_16x16x32_f16(a, BfI[0][kc], acc0, 0, 0, 0);
                acc1 = __builtin_amdgcn_mfma_f32_16x16x32_f16(a, BfI[1][kc], acc1, 0, 0, 0);
            }
            if (t > 0) {
                const f16* sb = stage[p];
#pragma unroll
                for (int kc = 0; kc < 16; ++kc) {
                    half8 a = *(const half8*)&sb[lr * 512 + (((kc * 4 + quad) ^ (lr & 7)) * 8)];
                    acc0 = __builtin_amdgcn_mfma_f32_16x16x32_f16(a, BfH[0][kc], acc0, 0, 0, 0);
                    acc1 = __builtin_amdgcn_mfma_f32_16x16x32_f16(a, BfH[1][kc], acc1, 0, 0, 0);
                }
            }

            // [E] h1_t = relu(acc + bias1); own slice -> stage[np].
            f16* sw = stage[np];
            f16 hv16[2][4];
#pragma unroll
            for (int j = 0; j < 2; ++j) {
                const float4v& a = j ? acc1 : acc0;
#pragma unroll
                for (int i = 0; i < 4; ++i) {
                    float hval = fmaxf(a[i] + bvv[j], 0.f);
                    hv16[j][i] = (f16)hval;
                    int row = quad * 4 + i, lc = c0w + j * 16 + lr;
                    sw[row * 512 + ((lc >> 3) ^ (row & 7)) * 8 + (lc & 7)] = hv16[j][i];
                }
            }
            if (h_last && t == T_LEN - 1) {
#pragma unroll
                for (int j = 0; j < 2; ++j)
#pragma unroll
                    for (int i = 0; i < 4; ++i)
                        h_last[(size_t)(rows0 + quad * 4 + i) * H_DIM + c0w + j * 16 + lr] =
                            (float)hv16[j][i];
            }
            if (tt == Tc - 1) {
#pragma unroll
                for (int j = 0; j < 2; ++j)
#pragma unroll
                    for (int i = 0; i < 4; ++i)
                        hc1[(size_t)(rows0 + quad * 4 + i) * H_DIM + c0w + j * 16 + lr] =
                            hv16[j][i];
            }
            __syncthreads();   // own-slice stage writes visible to publishers

            // [F] publish h1_t to hex1; issue sibling + next-h0 loads.
            {
                int row = tid >> 4, poc = (tid & 15) * 2, cu = cg * 32 + poc;
                uint4 q4 = *(const uint4*)&stage[np][row * 512 + (((cu >> 1) ^ (row & 7)) * 8)];
                u64 v0 = (((u64)q4.y) << 32) | q4.x;
                u64 v1 = (((u64)q4.w) << 32) | q4.z;
                u64* dst = hex1 + ((size_t)np * 64 + rows0 + row) * 128;
                astore(&dst[cu], v0 | em);
                astore(&dst[cu + 1], v1 | em);
            }
            if (!mine) {
                u64* src = hex1 + ((size_t)np * 64 + rows0 + rrow) * 128;
#pragma unroll
                for (int q = 0; q < 8; ++q) sv[q] = aload(&src[rc8 + q]);
            }
            if (tt + 1 < Tc) {
                u64* srcn = hex0 + ((size_t)((t + 1) & 7) * 64 + rows0 + rrow) * 128;
#pragma unroll
                for (int q = 0; q < 8; ++q) vv[q] = aload(&srcn[rc8 + q]);
            }
        }
    }
}

// --------------------------- final FC --------------------------------------
__global__ void fc_kernel(const float* __restrict__ hlast, const f16* __restrict__ fcw,
                          const float* __restrict__ fcb, void* __restrict__ out,
                          const int* __restrict__ dtf) {
    int b = blockIdx.x, c = threadIdx.x;
    const float* hrow = hlast + b * H_DIM;
    const f16* wrow = fcw + (size_t)c * H_DIM;
    float s = fcb[c];
    for (int h0 = 0; h0 < H_DIM; h0 += 8) {
        half8 w = *(const half8*)(wrow + h0);
#pragma unroll
        for (int j = 0; j < 8; ++j) s += hrow[h0 + j] * (float)w[j];
    }
    if (*dtf) ((float*)out)[b * 128 + c] = s;
    else      ((u16*)out)[b * 128 + c] = f2bf(s);
}

// --------------------------- launch ----------------------------------------
extern "C" void kernel_launch(void* const* d_in, const int* in_sizes, int n_in,
                              void* d_out, int out_size, void* d_ws, size_t ws_size,
                              hipStream_t stream)
{
    const void* x     = d_in[0];
    const void* W_ih0 = d_in[1];
    const void* W_hh0 = d_in[2];
    const void* b_ih0 = d_in[3];
    const void* b_hh0 = d_in[4];
    const void* W_ih1 = d_in[5];
    const void* W_hh1 = d_in[6];
    const void* b_ih1 = d_in[7];
    const void* b_hh1 = d_in[8];
    const void* fc_w  = d_in[9];
    const void* fc_b  = d_in[10];

    char* ws = (char*)d_ws;
    int*   dtf   = (int*)(ws + 0);            //     64 B
    float* bias0 = (float*)(ws + 4096);       //   2048 B
    float* bias1 = (float*)(ws + 6144);       //   2048 B
    float* fcbf  = (float*)(ws + 8192);       //    512 B
    u32*   prog  = (u32*)(ws + 12288);        //     64 B
    float* hlast = (float*)(ws + 16384);      // 131072 B
    f16*   hc0   = (f16*)(ws + 147456);       //  65536 B
    f16*   hc1   = (f16*)(ws + 212992);       //  65536 B
    u64*   hex0  = (u64*)(ws + 278528);       // 524288 B [8][64][128] u64 ring
    u64*   hex1  = (u64*)(ws + 802816);       // 131072 B [2][64][128]
    f16*   Wih0f = (f16*)(ws + 933888);       // 262144 B
    f16*   Whh0f = (f16*)(ws + 1196032);      // 524288 B
    f16*   Wih1f = (f16*)(ws + 1720320);      // 524288 B
    f16*   Whh1f = (f16*)(ws + 2244608);      // 524288 B
    f16*   fcwf  = (f16*)(ws + 2768896);      // 131072 B

    const size_t misc = 4u << 20;
    int Tc = 128;
    {
        auto need = [&](int tc) {
            return misc + (size_t)B_SZ * (size_t)tc * H_DIM * 2;   // single buffer
        };
        if (ws_size >= need(2048)) Tc = 2048;
        else if (ws_size >= need(1024)) Tc = 1024;
        else if (ws_size >= need(512)) Tc = 512;
        else if (ws_size >= need(256)) Tc = 256;
        else Tc = 128;
    }
    int lgTc = 31 - __builtin_clz((unsigned)Tc);
    f16* bufA = (f16*)(ws + misc);

    detect_kernel<<<dim3(1), dim3(64), 0, stream>>>((const u16*)x, dtf, prog);
    cvt_w_kernel<<<dim3(512), dim3(256), 0, stream>>>(W_ih0, Wih0f, H_DIM * 256, dtf);
    cvt_w_kernel<<<dim3(1024), dim3(256), 0, stream>>>(W_hh0, Whh0f, H_DIM * H_DIM, dtf);
    cvt_w_kernel<<<dim3(1024), dim3(256), 0, stream>>>(W_ih1, Wih1f, H_DIM * H_DIM, dtf);
    cvt_w_kernel<<<dim3(1024), dim3(256), 0, stream>>>(W_hh1, Whh1f, H_DIM * H_DIM, dtf);
    cvt_w_kernel<<<dim3(256), dim3(256), 0, stream>>>(fc_w, fcwf, 128 * H_DIM, dtf);
    bias_kernel<<<dim3(2), dim3(256), 0, stream>>>(b_ih0, b_hh0, bias0, dtf);
    bias_kernel<<<dim3(2), dim3(256), 0, stream>>>(b_ih1, b_hh1, bias1, dtf);
    fcb_kernel<<<dim3(1), dim3(128), 0, stream>>>(fc_b, fcbf, dtf);

    const int NC = T_LEN / Tc;
    const int mblocks = B_SZ * Tc / 64;
    for (int c = 0; c < NC; ++c) {
        const int t0 = c * Tc;
        gemm_tiled<1><<<dim3(mblocks, 8), 256, 0, stream>>>(
            x, Wih0f, bias0, bufA, lgTc, t0, 256, dtf);
        rnn_fused_scan<<<dim3(32), 256, 0, stream>>>(
            bufA, Whh0f, Wih1f, Whh1f, bias1, hex0, hex1, hc0, hc1, prog,
            t0, Tc, hlast);
    }
    fc_kernel<<<dim3(B_SZ), dim3(128), 0, stream>>>(hlast, fcwf, fcbf, d_out, dtf);
}

// Round 5
// 7715.598 us; speedup vs baseline: 1.4012x; 1.2046x over previous
//
#include <hip/hip_runtime.h>

// ---------------------------------------------------------------------------
// 2-layer ReLU RNN, B=64 T=2048 IN=256 H=512 C=128. fp32 inputs (runtime
// dtype detect kept), output dtype matches input.
//
// Round-10: 3-role pipeline. Layer-1's input projection (Wih1 h0_t, no
// recurrent dependency) moves OFF the latency-critical recurrent loop into
// 16 dedicated projection WGs. Grid = 48:
//   role 0 (L0,   16 WG): layer-0 scan, publishes h0 -> hex0 (8-ring).
//   role 2 (PROJ, 16 WG): consumes hex0, computes z = Wih1 h0 + b1,
//           publishes pos=relu(z), neg=relu(-z) (sign bits free -> 4-bit
//           step tag works) col-major-packed (4 rows per u64) -> hexZ
//           (8-ring). No sibling exchange -> never rate-limiting.
//   role 1 (L1REC,16 WG): h1_t = relu(z_t + Whh1 h1_{t-1}) -- K=512 only,
//           same weight as layer-0. z arrives via register prefetch
//           (proj leads), no LDS staging (u64 = 4 rows of one col).
// Throttles (all LAG=7 <= ring-1): L0 waits progProj >= t-6 (hex0 reuse);
// PROJ waits progL1 >= t-6 (hexZ reuse). Acyclic: every wait targets a
// strictly earlier step. All spins guard-limited -> no hangs.
// XCD co-location: sibling sets {L0,r} and {L1REC,r} mapped to bids
// congruent mod 8 (round-robin dispatch puts them on one XCD; if the
// mapping assumption is wrong this is perf-neutral, never incorrect).
// ---------------------------------------------------------------------------

typedef unsigned short u16;
typedef unsigned int u32;
typedef unsigned long long u64;
typedef _Float16 f16;
typedef _Float16 half8 __attribute__((ext_vector_type(8)));
typedef float float4v __attribute__((ext_vector_type(4)));

#define T_LEN 2048
#define H_DIM 512
#define B_SZ 64
#define SGN 0x8000800080008000ull
#define VMASK 0x7fff7fff7fff7fffull
#define SPIN_LIM (1 << 15)
#define LAG 7

__device__ __forceinline__ float bf2f(u16 u) {
    union { u32 i; float f; } v; v.i = ((u32)u) << 16; return v.f;
}
__device__ __forceinline__ u16 f2bf(float f) {
    u32 x = __float_as_uint(f);
    u32 r = (x + 0x7fffu + ((x >> 16) & 1u)) >> 16;
    return (u16)r;
}
__device__ __forceinline__ float loadf(const void* p, size_t i, int dt) {
    return dt ? ((const float*)p)[i] : bf2f(((const u16*)p)[i]);
}
__device__ __forceinline__ half8 cvt8_bf16(uint4 v) {
    half8 h;
    h[0] = (f16)bf2f((u16)(v.x & 0xffff)); h[1] = (f16)bf2f((u16)(v.x >> 16));
    h[2] = (f16)bf2f((u16)(v.y & 0xffff)); h[3] = (f16)bf2f((u16)(v.y >> 16));
    h[4] = (f16)bf2f((u16)(v.z & 0xffff)); h[5] = (f16)bf2f((u16)(v.z >> 16));
    h[6] = (f16)bf2f((u16)(v.w & 0xffff)); h[7] = (f16)bf2f((u16)(v.w >> 16));
    return h;
}
// 4-bit tag (t & 15) in the 4 f16 sign bits of a u64.
__device__ __forceinline__ u64 tagmask(int t) {
    return ((t & 1) ? 0x0000000000008000ull : 0ull) |
           ((t & 2) ? 0x0000000080000000ull : 0ull) |
           ((t & 4) ? 0x0000800000000000ull : 0ull) |
           ((t & 8) ? 0x8000000000000000ull : 0ull);
}
__device__ __forceinline__ u64 aload(u64* p) {
    return __hip_atomic_load(p, __ATOMIC_RELAXED, __HIP_MEMORY_SCOPE_AGENT);
}
__device__ __forceinline__ void astore(u64* p, u64 v) {
    __hip_atomic_store(p, v, __ATOMIC_RELAXED, __HIP_MEMORY_SCOPE_AGENT);
}
__device__ __forceinline__ u32 aload32(u32* p) {
    return __hip_atomic_load(p, __ATOMIC_RELAXED, __HIP_MEMORY_SCOPE_AGENT);
}
// Validate 8 in-flight words vs tag em; spin-reload misses from src[rc8+q].
__device__ __forceinline__ void validate8(u64* src, int rc8, u64 em, u64* vv) {
    int pend = 0;
#pragma unroll
    for (int q = 0; q < 8; ++q)
        if ((vv[q] & SGN) != em) pend |= 1 << q;
    int guard = 0;
    while (pend && guard < SPIN_LIM) {
#pragma unroll
        for (int q = 0; q < 8; ++q)
            if (pend & (1 << q)) vv[q] = aload(&src[rc8 + q]);
#pragma unroll
        for (int q = 0; q < 8; ++q)
            if ((pend & (1 << q)) && ((vv[q] & SGN) == em))
                pend &= ~(1 << q);
        ++guard;
    }
}
// Validate 4 in-flight words at scattered indices idx[q].
__device__ __forceinline__ void validate4i(u64* base, const int* idx, u64 em, u64* vv) {
    int pend = 0;
#pragma unroll
    for (int q = 0; q < 4; ++q)
        if ((vv[q] & SGN) != em) pend |= 1 << q;
    int guard = 0;
    while (pend && guard < SPIN_LIM) {
#pragma unroll
        for (int q = 0; q < 4; ++q)
            if (pend & (1 << q)) vv[q] = aload(&base[idx[q]]);
#pragma unroll
        for (int q = 0; q < 4; ++q)
            if ((pend & (1 << q)) && ((vv[q] & SGN) == em))
                pend &= ~(1 << q);
        ++guard;
    }
}

// --------------------------- dtype detection -------------------------------
__global__ void detect_kernel(const u16* __restrict__ xr, int* __restrict__ dtf,
                              u32* __restrict__ progP, u32* __restrict__ progL) {
    int lane = threadIdx.x;
    u16 u0 = xr[(lane * 2 + 0) * 2];
    u16 u1 = xr[(lane * 2 + 1) * 2];
    int e0 = (u0 >> 7) & 0xff, e1 = (u1 >> 7) & 0xff;
    int c0 = (e0 >= 0x60 && e0 <= 0x8f) ? 1 : 0;
    int c1 = (e1 >= 0x60 && e1 <= 0x8f) ? 1 : 0;
    int tot = __popcll(__ballot(c0)) + __popcll(__ballot(c1));
    if (lane == 0) *dtf = (tot >= 96) ? 0 : 1;   // 0 = bf16, 1 = fp32
    progP[lane] = 0;                             // 64 words each
    progL[lane] = 0;
}

// --------------------------- prep kernels ----------------------------------
__global__ void cvt_w_kernel(const void* __restrict__ in, f16* __restrict__ out,
                             int n, const int* __restrict__ dtf) {
    int dt = *dtf;
    for (int i = blockIdx.x * blockDim.x + threadIdx.x; i < n; i += gridDim.x * blockDim.x)
        out[i] = (f16)loadf(in, i, dt);
}

__global__ void bias_kernel(const void* __restrict__ bi, const void* __restrict__ bh,
                            float* __restrict__ bias, const int* __restrict__ dtf) {
    int dt = *dtf;
    int i = blockIdx.x * blockDim.x + threadIdx.x;
    if (i < H_DIM) bias[i] = loadf(bi, i, dt) + loadf(bh, i, dt);
}

__global__ void fcb_kernel(const void* __restrict__ in, float* __restrict__ out,
                           const int* __restrict__ dtf) {
    int i = threadIdx.x;
    if (i < 128) out[i] = loadf(in, i, *dtf);
}

// --------------------------- tiled MFMA GEMM -------------------------------
template<int RAW>
__global__ __launch_bounds__(256)
void gemm_tiled(const void* __restrict__ Araw, const f16* __restrict__ Bw,
                const float* __restrict__ bias, f16* __restrict__ C,
                int lgTc, int t_off, int K, const int* __restrict__ dtf)
{
    __shared__ f16 As[64][40];
    __shared__ f16 Bs[64][40];
    const int dt = RAW ? *dtf : 0;
    const int m0 = blockIdx.x * 64, n0 = blockIdx.y * 64;
    const int tid = threadIdx.x;
    const int wv = tid >> 6, lane = tid & 63;
    const int lr = lane & 15, quad = lane >> 4;
    const int srow = tid >> 2, skq = tid & 3;

    float4v acc[4] = {{0.f,0.f,0.f,0.f},{0.f,0.f,0.f,0.f},{0.f,0.f,0.f,0.f},{0.f,0.f,0.f,0.f}};

    size_t arow;
    {
        int ml = m0 + srow;
        if (RAW) {
            int b = ml >> lgTc, tt = ml & ((1 << lgTc) - 1);
            arow = (size_t)b * T_LEN + t_off + tt;
        } else arow = (size_t)ml;
    }
    const f16* pb = Bw + (size_t)(n0 + srow) * K + skq * 8;

    for (int k0 = 0; k0 < K; k0 += 32) {
        half8 av;
        if (RAW) {
            if (dt) {
                const float* ap = (const float*)Araw + arow * K + k0 + skq * 8;
                float4v f0 = *(const float4v*)ap;
                float4v f1 = *(const float4v*)(ap + 4);
                av[0]=(f16)f0[0]; av[1]=(f16)f0[1]; av[2]=(f16)f0[2]; av[3]=(f16)f0[3];
                av[4]=(f16)f1[0]; av[5]=(f16)f1[1]; av[6]=(f16)f1[2]; av[7]=(f16)f1[3];
            } else {
                av = cvt8_bf16(*(const uint4*)((const u16*)Araw + arow * K + k0 + skq * 8));
            }
        } else {
            av = *(const half8*)((const f16*)Araw + arow * K + k0 + skq * 8);
        }
        half8 bv = *(const half8*)(pb + k0);
        __syncthreads();
        *(half8*)&As[srow][skq * 8] = av;
        *(half8*)&Bs[srow][skq * 8] = bv;
        __syncthreads();
        half8 bf = *(const half8*)&Bs[wv * 16 + lr][quad * 8];
#pragma unroll
        for (int mt = 0; mt < 4; ++mt) {
            half8 af = *(const half8*)&As[mt * 16 + lr][quad * 8];
            acc[mt] = __builtin_amdgcn_mfma_f32_16x16x32_f16(af, bf, acc[mt], 0, 0, 0);
        }
    }
    const int n = n0 + wv * 16 + lr;
    const float bval = bias[n];
#pragma unroll
    for (int mt = 0; mt < 4; ++mt) {
#pragma unroll
        for (int i = 0; i < 4; ++i) {
            int m = m0 + mt * 16 + quad * 4 + i;
            C[(size_t)m * H_DIM + n] = (f16)(acc[mt][i] + bval);
        }
    }
}

// --------------------------- fused 3-role scan -----------------------------
// grid = 48. b<32: c=b&7: role=(c>>2) (0=L0,1=L1REC), r=b&3, cg=b>>3 --
// sibling sets share b%8 (one XCD under round-robin). b>=32: PROJ,
// r=(b-32)>>2, cg=(b-32)&3.
// hex0: [8][64][128] u64 (slot t&7, 4-bit tag). hex1: [2][64][128].
// hexZ: [8][4][4][1024] u64 -- per (slot,r,cg): pos[128 cols][4 quads] ++
// neg[...] col-major (u64 = rows quad*4..+3 of one col).
// progP[r*16+cg]: PROJ consumed h0_t -> t+1 (gates L0 publish, LAG=7).
// progL[r*16+cg]: L1REC consumed z_t -> t+1 (gates PROJ publish, LAG=7).
__global__ __launch_bounds__(256, 1)
void rnn_fused_scan(const f16* __restrict__ pre0,    // [B,Tc,H] chunk-local
                    const f16* __restrict__ Whh0,    // [H,H] fp16
                    const f16* __restrict__ Wih1,    // [H,H] fp16
                    const f16* __restrict__ Whh1,    // [H,H] fp16
                    const float* __restrict__ bias1, // [H] fp32
                    u64* __restrict__ hex0,          // [8][64][128]
                    u64* __restrict__ hex1,          // [2][64][128]
                    u64* __restrict__ hexZ,          // [8][4][4][1024]
                    f16* __restrict__ hc0,           // [B,H] layer-0 carry
                    f16* __restrict__ hc1,           // [B,H] layer-1 carry
                    u32* __restrict__ progP,         // [64] (r*16+cg used)
                    u32* __restrict__ progL,         // [64]
                    int t0, int Tc,
                    float* __restrict__ h_last)      // [B,H] fp32
{
    __shared__ f16 stage[2][16 * 512];   // L0/L1REC h double buffer
    __shared__ f16 sH0[16 * 512];        // PROJ h0 staging
    const int b = blockIdx.x;
    int role, r, cg;
    if (b < 32) { int c = b & 7; role = c >> 2; r = c & 3; cg = b >> 3; }
    else        { role = 2; r = (b - 32) >> 2; cg = (b - 32) & 3; }
    const int rows0 = r * 16;
    const int tid = threadIdx.x;
    const int w = tid >> 6, lane = tid & 63;
    const int lr = lane & 15, quad = lane >> 4;
    const int c0w = cg * 128 + w * 32;
    // Generic u64 coverage: thread covers u64-cols [rc8,rc8+8) of row rrow.
    const int rrow = tid >> 4;
    const int rc8 = (tid & 15) * 8;
    const bool mine = ((tid & 15) >> 2) == cg;

    if (role == 2) {
        // ========================= PROJECTION =========================
        half8 BfI[2][16];
#pragma unroll
        for (int j = 0; j < 2; ++j)
#pragma unroll
            for (int kc = 0; kc < 16; ++kc)
                BfI[j][kc] = *(const half8*)(Wih1 + (size_t)(c0w + j * 16 + lr) * H_DIM
                                             + kc * 32 + quad * 8);
        float bvv[2] = { bias1[c0w + lr], bias1[c0w + 16 + lr] };
        const int lc0 = w * 32 + lr, lc1 = lc0 + 16;   // local cols in slice

        u64 vv[8];
        {
            u64* src = hex0 + ((size_t)(t0 & 7) * 64 + rows0 + rrow) * 128;
#pragma unroll
            for (int q = 0; q < 8; ++q) vv[q] = aload(&src[rc8 + q]);
        }

        for (int tt = 0; tt < Tc; ++tt) {
            const int t = t0 + tt;
            const int nb = t & 7;
            const u64 em = tagmask(t);
            const int need = t - LAG;
            const u32 want = (u32)(need + 1);

            // Early throttle poll (hexZ slot reuse gate).
            u32 plv = 0xffffffffu;
            if (need >= 0) plv = aload32(&progL[r * 16 + cg]);

            // [A] validate h0_t -> sH0.
            {
                u64* src = hex0 + ((size_t)nb * 64 + rows0 + rrow) * 128;
                validate8(src, rc8, em, vv);
#pragma unroll
                for (int q = 0; q < 8; ++q) {
                    int cu = rc8 + q;
                    *(u64*)&sH0[rrow * 512 + ((cu >> 1) ^ (rrow & 7)) * 8 + (cu & 1) * 4] =
                        vv[q] & VMASK;
                }
            }
            __syncthreads();
            if (tid == 0)
                __hip_atomic_store(&progP[r * 16 + cg], (u32)(t + 1), __ATOMIC_RELAXED,
                                   __HIP_MEMORY_SCOPE_AGENT);

            // [D] z = Wih1 h0 (K=512).
            float4v acc0 = {0.f,0.f,0.f,0.f}, acc1 = {0.f,0.f,0.f,0.f};
#pragma unroll
            for (int kc = 0; kc < 16; ++kc) {
                half8 a = *(const half8*)&sH0[lr * 512 + (((kc * 4 + quad) ^ (lr & 7)) * 8)];
                acc0 = __builtin_amdgcn_mfma_f32_16x16x32_f16(a, BfI[0][kc], acc0, 0, 0, 0);
                acc1 = __builtin_amdgcn_mfma_f32_16x16x32_f16(a, BfI[1][kc], acc1, 0, 0, 0);
            }

            // [E] pack pos/neg col-major u64s (4 rows of one col).
            u64 zw[4];
#pragma unroll
            for (int j = 0; j < 2; ++j) {
                const float4v& a = j ? acc1 : acc0;
                u64 wp = 0, wn = 0;
#pragma unroll
                for (int i = 0; i < 4; ++i) {
                    float z = a[i] + bvv[j];
                    union { f16 h; u16 u; } cp, cn;
                    cp.h = (f16)fmaxf(z, 0.f);
                    cn.h = (f16)fmaxf(-z, 0.f);
                    wp |= ((u64)cp.u) << (16 * i);
                    wn |= ((u64)cn.u) << (16 * i);
                }
                zw[j] = wp; zw[2 + j] = wn;
            }
            __syncthreads();   // all waves done reading sH0 (next [A] rewrites)

            // Throttle resolve: publishing z_t destroys z_{t-8}; progL>=t-6
            // certifies L1REC consumed t-7 >= t-8.
            if (need >= 0) {
                int g = 0;
                while (plv < want && g < SPIN_LIM) {
                    plv = aload32(&progL[r * 16 + cg]);
                    ++g;
                }
            }

            // [F] publish 4 u64 (tagged); prefetch next h0.
            {
                u64* dz = hexZ + ((((size_t)nb * 4 + r) * 4 + cg) * 1024);
                astore(&dz[lc0 * 4 + quad],        zw[0] | em);
                astore(&dz[lc1 * 4 + quad],        zw[1] | em);
                astore(&dz[512 + lc0 * 4 + quad],  zw[2] | em);
                astore(&dz[512 + lc1 * 4 + quad],  zw[3] | em);
            }
            if (tt + 1 < Tc) {
                u64* srcn = hex0 + ((size_t)((t + 1) & 7) * 64 + rows0 + rrow) * 128;
#pragma unroll
                for (int q = 0; q < 8; ++q) vv[q] = aload(&srcn[rc8 + q]);
            }
        }
        return;
    }

    // ===================== L0 (role 0) / L1REC (role 1) =====================
    const f16* Wrec = (role == 0) ? Whh0 : Whh1;
    half8 Bf[2][16];
#pragma unroll
    for (int j = 0; j < 2; ++j)
#pragma unroll
        for (int kc = 0; kc < 16; ++kc)
            Bf[j][kc] = *(const half8*)(Wrec + (size_t)(c0w + j * 16 + lr) * H_DIM
                                        + kc * 32 + quad * 8);
    f16* hcarry = (role == 0) ? hc0 : hc1;
    u64* hexOwn = (role == 0) ? hex0 : hex1;

    if (t0 > 0) {
        int row = tid >> 4, g0 = (tid & 15) * 4;
#pragma unroll
        for (int gq = 0; gq < 4; ++gq) {
            int g = g0 + gq;
            *(uint4*)&stage[(t0 - 1) & 1][row * 512 + ((g ^ (row & 7)) * 8)] =
                *(const uint4*)(hcarry + (size_t)(rows0 + row) * H_DIM + g * 8);
        }
    }
    __syncthreads();

    u64 sv[8];                 // in-flight sibling words (step t-1)
    float pv[2][4];            // L0: pre_t (pipelined)
    u64 vvz[4];                // L1REC: in-flight z words (step t)
    int idxz[4];
    const int lc0 = w * 32 + lr, lc1 = lc0 + 16;
    idxz[0] = lc0 * 4 + quad;       idxz[1] = lc1 * 4 + quad;
    idxz[2] = 512 + lc0 * 4 + quad; idxz[3] = 512 + lc1 * 4 + quad;

    if (role == 0) {
#pragma unroll
        for (int j = 0; j < 2; ++j)
#pragma unroll
            for (int i = 0; i < 4; ++i)
                pv[j][i] = (float)pre0[((size_t)(rows0 + quad * 4 + i) * Tc + 0) * H_DIM
                                       + c0w + j * 16 + lr];
    } else {
        u64* zb = hexZ + ((((size_t)(t0 & 7) * 4 + r) * 4 + cg) * 1024);
#pragma unroll
        for (int q = 0; q < 4; ++q) vvz[q] = aload(&zb[idxz[q]]);
    }

    for (int tt = 0; tt < Tc; ++tt) {
        const int t = t0 + tt;
        const int p = (t - 1) & 1, np = t & 1;
        const u64 em = tagmask(t);
        const int nbOwn = (role == 0) ? (t & 7) : (t & 1);   // own publish slot
        const int need = t - LAG;
        const u32 want = (u32)(need + 1);

        // L0 early throttle poll (hex0 slot reuse gate, per row-group).
        u32 ppv = 0xffffffffu;
        if (role == 0 && need >= 0 && lane < 4)
            ppv = aload32(&progP[r * 16 + lane]);

        // [A] validate in-flight sibling words of step t-1 -> stage[p].
        if (tt > 0 && !mine) {
            u64* src;
            if (role == 0)
                src = hex0 + ((size_t)((t - 1) & 7) * 64 + rows0 + rrow) * 128;
            else
                src = hex1 + ((size_t)((t - 1) & 1) * 64 + rows0 + rrow) * 128;
            validate8(src, rc8, tagmask(t - 1), sv);
#pragma unroll
            for (int q = 0; q < 8; ++q) {
                int cu = rc8 + q;
                *(u64*)&stage[p][rrow * 512 + ((cu >> 1) ^ (rrow & 7)) * 8 + (cu & 1) * 4] =
                    sv[q] & VMASK;
            }
        }
        __syncthreads();   // stage[p] complete

        // [D] recurrent MFMA chain (K=512).
        float4v acc0 = {0.f,0.f,0.f,0.f}, acc1 = {0.f,0.f,0.f,0.f};
        if (t > 0) {
            const f16* sb = stage[p];
#pragma unroll
            for (int kc = 0; kc < 16; ++kc) {
                half8 a = *(const half8*)&sb[lr * 512 + (((kc * 4 + quad) ^ (lr & 7)) * 8)];
                acc0 = __builtin_amdgcn_mfma_f32_16x16x32_f16(a, Bf[0][kc], acc0, 0, 0, 0);
                acc1 = __builtin_amdgcn_mfma_f32_16x16x32_f16(a, Bf[1][kc], acc1, 0, 0, 0);
            }
        }

        // L1REC: validate z_t (usually resident), report consumption.
        if (role == 1) {
            u64* zb = hexZ + ((((size_t)(t & 7) * 4 + r) * 4 + cg) * 1024);
            validate4i(zb, idxz, em, vvz);
            if (tid == 0)
                __hip_atomic_store(&progL[r * 16 + cg], (u32)(t + 1), __ATOMIC_RELAXED,
                                   __HIP_MEMORY_SCOPE_AGENT);
#pragma unroll
            for (int j = 0; j < 2; ++j) {
                u64 pw = vvz[j] & VMASK, nw = vvz[2 + j] & VMASK;
#pragma unroll
                for (int i = 0; i < 4; ++i) {
                    union { u16 u; f16 h; } cp, cn;
                    cp.u = (u16)(pw >> (16 * i));
                    cn.u = (u16)(nw >> (16 * i));
                    pv[j][i] = (float)cp.h - (float)cn.h;
                }
            }
        }

        // [E] h_t = relu(acc + pv); own slice -> stage[np].
        f16* swp = stage[np];
        f16 hv16[2][4];
#pragma unroll
        for (int j = 0; j < 2; ++j) {
            const float4v& a = j ? acc1 : acc0;
#pragma unroll
            for (int i = 0; i < 4; ++i) {
                float hval = fmaxf(a[i] + pv[j][i], 0.f);
                hv16[j][i] = (f16)hval;
                int row = quad * 4 + i, lc = c0w + j * 16 + lr;
                swp[row * 512 + ((lc >> 3) ^ (row & 7)) * 8 + (lc & 7)] = hv16[j][i];
            }
        }
        if (role == 1 && h_last && t == T_LEN - 1) {
#pragma unroll
            for (int j = 0; j < 2; ++j)
#pragma unroll
                for (int i = 0; i < 4; ++i)
                    h_last[(size_t)(rows0 + quad * 4 + i) * H_DIM + c0w + j * 16 + lr] =
                        (float)hv16[j][i];
        }
        if (tt == Tc - 1) {
#pragma unroll
            for (int j = 0; j < 2; ++j)
#pragma unroll
                for (int i = 0; i < 4; ++i)
                    hcarry[(size_t)(rows0 + quad * 4 + i) * H_DIM + c0w + j * 16 + lr] =
                        hv16[j][i];
        }
        __syncthreads();   // stage[np] own slices visible to publishers

        // L0 throttle resolve: publishing t destroys hex0 slot of t-8; PROJ
        // (the laggiest consumer) must have consumed t-7.
        if (role == 0 && need >= 0) {
            bool ok = __all((lane < 4) ? (ppv >= want) : 1);
            int g = 0;
            while (!ok && g < SPIN_LIM) {
                if (lane < 4) ppv = aload32(&progP[r * 16 + lane]);
                ok = __all((lane < 4) ? (ppv >= want) : 1);
                ++g;
            }
        }

        // [F] publish own 2 u64 (tagged); issue sibling loads; prefetch.
        {
            int row = tid >> 4, poc = (tid & 15) * 2, cu = cg * 32 + poc;
            uint4 q4 = *(const uint4*)&stage[np][row * 512 + (((cu >> 1) ^ (row & 7)) * 8)];
            u64 v0 = (((u64)q4.y) << 32) | q4.x;
            u64 v1 = (((u64)q4.w) << 32) | q4.z;
            u64* dst = hexOwn + ((size_t)nbOwn * 64 + rows0 + row) * 128;
            astore(&dst[cu], v0 | em);
            astore(&dst[cu + 1], v1 | em);
        }
        if (!mine) {
            u64* src = hexOwn + ((size_t)nbOwn * 64 + rows0 + rrow) * 128;
#pragma unroll
            for (int q = 0; q < 8; ++q) sv[q] = aload(&src[rc8 + q]);
        }
        if (tt + 1 < Tc) {
            if (role == 0) {
#pragma unroll
                for (int j = 0; j < 2; ++j)
#pragma unroll
                    for (int i = 0; i < 4; ++i)
                        pv[j][i] = (float)pre0[((size_t)(rows0 + quad * 4 + i) * Tc + tt + 1)
                                               * H_DIM + c0w + j * 16 + lr];
            } else {
                u64* zb = hexZ + ((((size_t)((t + 1) & 7) * 4 + r) * 4 + cg) * 1024);
#pragma unroll
                for (int q = 0; q < 4; ++q) vvz[q] = aload(&zb[idxz[q]]);
            }
        }
    }
}

// --------------------------- final FC --------------------------------------
__global__ void fc_kernel(const float* __restrict__ hlast, const f16* __restrict__ fcw,
                          const float* __restrict__ fcb, void* __restrict__ out,
                          const int* __restrict__ dtf) {
    int b = blockIdx.x, c = threadIdx.x;
    const float* hrow = hlast + b * H_DIM;
    const f16* wrow = fcw + (size_t)c * H_DIM;
    float s = fcb[c];
    for (int h0 = 0; h0 < H_DIM; h0 += 8) {
        half8 w = *(const half8*)(wrow + h0);
#pragma unroll
        for (int j = 0; j < 8; ++j) s += hrow[h0 + j] * (float)w[j];
    }
    if (*dtf) ((float*)out)[b * 128 + c] = s;
    else      ((u16*)out)[b * 128 + c] = f2bf(s);
}

// --------------------------- launch ----------------------------------------
extern "C" void kernel_launch(void* const* d_in, const int* in_sizes, int n_in,
                              void* d_out, int out_size, void* d_ws, size_t ws_size,
                              hipStream_t stream)
{
    const void* x     = d_in[0];
    const void* W_ih0 = d_in[1];
    const void* W_hh0 = d_in[2];
    const void* b_ih0 = d_in[3];
    const void* b_hh0 = d_in[4];
    const void* W_ih1 = d_in[5];
    const void* W_hh1 = d_in[6];
    const void* b_ih1 = d_in[7];
    const void* b_hh1 = d_in[8];
    const void* fc_w  = d_in[9];
    const void* fc_b  = d_in[10];

    char* ws = (char*)d_ws;
    int*   dtf   = (int*)(ws + 0);            //     64 B
    float* bias0 = (float*)(ws + 4096);       //   2048 B
    float* bias1 = (float*)(ws + 6144);       //   2048 B
    float* fcbf  = (float*)(ws + 8192);       //    512 B
    u32*   progP = (u32*)(ws + 12288);        //    256 B
    u32*   progL = (u32*)(ws + 12544);        //    256 B
    float* hlast = (float*)(ws + 16384);      // 131072 B
    f16*   hc0   = (f16*)(ws + 147456);       //  65536 B
    f16*   hc1   = (f16*)(ws + 212992);       //  65536 B
    u64*   hex0  = (u64*)(ws + 278528);       // 524288 B [8][64][128]
    u64*   hex1  = (u64*)(ws + 802816);       // 131072 B [2][64][128]
    u64*   hexZ  = (u64*)(ws + 933888);       // 1048576 B [8][4][4][1024]
    f16*   Wih0f = (f16*)(ws + 1982464);      // 262144 B
    f16*   Whh0f = (f16*)(ws + 2244608);      // 524288 B
    f16*   Wih1f = (f16*)(ws + 2768896);      // 524288 B
    f16*   Whh1f = (f16*)(ws + 3293184);      // 524288 B
    f16*   fcwf  = (f16*)(ws + 3817472);      // 131072 B  (ends 3948544 < 4MB)

    const size_t misc = 4u << 20;
    int Tc = 128;
    {
        auto need = [&](int tc) {
            return misc + (size_t)B_SZ * (size_t)tc * H_DIM * 2;
        };
        if (ws_size >= need(2048)) Tc = 2048;
        else if (ws_size >= need(1024)) Tc = 1024;
        else if (ws_size >= need(512)) Tc = 512;
        else if (ws_size >= need(256)) Tc = 256;
        else Tc = 128;
    }
    int lgTc = 31 - __builtin_clz((unsigned)Tc);
    f16* bufA = (f16*)(ws + misc);

    detect_kernel<<<dim3(1), dim3(64), 0, stream>>>((const u16*)x, dtf, progP, progL);
    cvt_w_kernel<<<dim3(512), dim3(256), 0, stream>>>(W_ih0, Wih0f, H_DIM * 256, dtf);
    cvt_w_kernel<<<dim3(1024), dim3(256), 0, stream>>>(W_hh0, Whh0f, H_DIM * H_DIM, dtf);
    cvt_w_kernel<<<dim3(1024), dim3(256), 0, stream>>>(W_ih1, Wih1f, H_DIM * H_DIM, dtf);
    cvt_w_kernel<<<dim3(1024), dim3(256), 0, stream>>>(W_hh1, Whh1f, H_DIM * H_DIM, dtf);
    cvt_w_kernel<<<dim3(256), dim3(256), 0, stream>>>(fc_w, fcwf, 128 * H_DIM, dtf);
    bias_kernel<<<dim3(2), dim3(256), 0, stream>>>(b_ih0, b_hh0, bias0, dtf);
    bias_kernel<<<dim3(2), dim3(256), 0, stream>>>(b_ih1, b_hh1, bias1, dtf);
    fcb_kernel<<<dim3(1), dim3(128), 0, stream>>>(fc_b, fcbf, dtf);

    const int NC = T_LEN / Tc;
    const int mblocks = B_SZ * Tc / 64;
    for (int c = 0; c < NC; ++c) {
        const int t0 = c * Tc;
        gemm_tiled<1><<<dim3(mblocks, 8), 256, 0, stream>>>(
            x, Wih0f, bias0, bufA, lgTc, t0, 256, dtf);
        rnn_fused_scan<<<dim3(48), 256, 0, stream>>>(
            bufA, Whh0f, Wih1f, Whh1f, bias1, hex0, hex1, hexZ, hc0, hc1,
            progP, progL, t0, Tc, hlast);
    }
    fc_kernel<<<dim3(B_SZ), dim3(128), 0, stream>>>(hlast, fcwf, fcbf, d_out, dtf);
}